// Round 3
// baseline (744.331 us; speedup 1.0000x reference)
//
#include <hip/hip_runtime.h>
#include <hip/hip_bf16.h>

#define T_STEPS 2048
#define BATCH 16
#define DIM 1024
#define EPSV 1e-6f
#define SLOTF (BATCH * DIM)      // floats per [B][D] slot
#define SLOT4C (BATCH * DIM / 4) // float4 per slot

typedef short short8 __attribute__((ext_vector_type(8)));
typedef float f32x4 __attribute__((ext_vector_type(4)));

struct alignas(16) bf16x8pack { __hip_bfloat16 v[8]; };

// ---------------- fp32 -> bf16 convert (vectorized) ----------------
__global__ __launch_bounds__(256) void cvt_kernel(const float* __restrict__ src,
                                                  bf16x8pack* __restrict__ dst, int n8) {
  int i = blockIdx.x * blockDim.x + threadIdx.x;
  if (i >= n8) return;
  const float4* s4 = (const float4*)src + (size_t)i * 2;
  float4 a = s4[0];
  float4 b = s4[1];
  bf16x8pack p;
  p.v[0] = __float2bfloat16(a.x); p.v[1] = __float2bfloat16(a.y);
  p.v[2] = __float2bfloat16(a.z); p.v[3] = __float2bfloat16(a.w);
  p.v[4] = __float2bfloat16(b.x); p.v[5] = __float2bfloat16(b.y);
  p.v[6] = __float2bfloat16(b.z); p.v[7] = __float2bfloat16(b.w);
  dst[i] = p;
}

// ---------------- bf16 MFMA GEMM: out[m][e] = alpha*(sum_d X[m][d]*W[e][d] + b[e]) ----
__global__ __launch_bounds__(256) void gemm_kernel(
    const __hip_bfloat16* __restrict__ Xb,
    const __hip_bfloat16* __restrict__ Wb,
    const float* __restrict__ bias,
    const float* __restrict__ log_alpha_p,
    float* __restrict__ hreg) {
  __shared__ __hip_bfloat16 As[128 * 32];
  __shared__ __hip_bfloat16 Bs[128 * 32];
  const int tid = threadIdx.x;
  const int wave = tid >> 6, lane = tid & 63;
  const int m0 = blockIdx.y * 128;
  const int e0 = blockIdx.x * 128;
  const int wm = (wave >> 1) * 64;
  const int wn = (wave & 1) * 64;
  const int l15 = lane & 15, l4 = lane >> 4;

  f32x4 acc[4][4] = {};

  const int srow = wave * 16 + (lane >> 2);
  const int sch = (lane & 3) * 8;

  for (int kt = 0; kt < DIM; kt += 32) {
    __syncthreads();
#pragma unroll
    for (int i = 0; i < 2; ++i) {
      const __hip_bfloat16* ga = Xb + (size_t)(m0 + i * 64 + srow) * DIM + kt + sch;
      const __hip_bfloat16* gb = Wb + (size_t)(e0 + i * 64 + srow) * DIM + kt + sch;
      __builtin_amdgcn_global_load_lds(
          (const __attribute__((address_space(1))) void*)ga,
          (__attribute__((address_space(3))) void*)((char*)As + (i * 64 + wave * 16) * 64),
          16, 0, 0);
      __builtin_amdgcn_global_load_lds(
          (const __attribute__((address_space(1))) void*)gb,
          (__attribute__((address_space(3))) void*)((char*)Bs + (i * 64 + wave * 16) * 64),
          16, 0, 0);
    }
    __syncthreads();
    short8 a[4], b[4];
#pragma unroll
    for (int f = 0; f < 4; ++f)
      a[f] = *(const short8*)((const char*)As + ((wm + f * 16 + l15) * 32 + l4 * 8) * 2);
#pragma unroll
    for (int g = 0; g < 4; ++g)
      b[g] = *(const short8*)((const char*)Bs + ((wn + g * 16 + l15) * 32 + l4 * 8) * 2);
#pragma unroll
    for (int f = 0; f < 4; ++f)
#pragma unroll
      for (int g = 0; g < 4; ++g)
        acc[f][g] = __builtin_amdgcn_mfma_f32_16x16x32_bf16(a[f], b[g], acc[f][g], 0, 0, 0);
  }
  const float alpha = __expf(log_alpha_p[0]);
#pragma unroll
  for (int g = 0; g < 4; ++g) {
    const int e = e0 + wn + g * 16 + l15;
    const float bv = bias[e];
#pragma unroll
    for (int f = 0; f < 4; ++f) {
#pragma unroll
      for (int r = 0; r < 4; ++r) {
        const int m = m0 + wm + f * 16 + l4 * 4 + r;
        hreg[(size_t)(m + BATCH) * DIM + e] = alpha * (acc[f][g][r] + bv);
      }
    }
  }
}

// ---------------- DPP wave-sum helpers (total lands in lane 63) ----------------
__device__ __forceinline__ float dpp_sum_reg(float x) {
  float acc = x;
#define DPP_ADD(ctrl)                                                              \
  {                                                                                \
    int t_ = __builtin_amdgcn_update_dpp(0, __float_as_int(acc), (ctrl), 0xf, 0xf, \
                                         true);                                    \
    acc += __int_as_float(t_);                                                     \
  }
  DPP_ADD(0x111); DPP_ADD(0x112); DPP_ADD(0x114); DPP_ADD(0x118);
  DPP_ADD(0x142); DPP_ADD(0x143);
#undef DPP_ADD
  return acc;
}
__device__ __forceinline__ float lane63(float v) {
  return __int_as_float(__builtin_amdgcn_readlane(__float_as_int(v), 63));
}

// ---------------- precompute e_t=||W_t||^2, d_t=W_{t-1}.W_t, d2_t=W_{t-2}.W_t ------
// W_t row (b) lives at hreg slot t+1, row b. scal4[b*T + t] = (e,d,d2,0).
__global__ __launch_bounds__(64) void dots_kernel(const float* __restrict__ hreg,
                                                  float4* __restrict__ scal4) {
  const int t = blockIdx.x >> 4;
  const int b = blockIdx.x & 15;
  const int lane = threadIdx.x;
  const float4* w  = (const float4*)(hreg + (size_t)(t + 1) * SLOTF + b * DIM);
  const float4* m1 = (const float4*)(hreg + (size_t)(t    ) * SLOTF + b * DIM);
  const float4* m2 = (const float4*)(hreg + (size_t)(t - 1) * SLOTF + b * DIM);
  float e = 0.f, d = 0.f, d2 = 0.f;
#pragma unroll
  for (int j = 0; j < 4; ++j) {
    float4 a = w[lane + 64 * j];
    e = fmaf(a.x, a.x, fmaf(a.y, a.y, fmaf(a.z, a.z, fmaf(a.w, a.w, e))));
    if (t >= 1) {
      float4 p = m1[lane + 64 * j];
      d = fmaf(p.x, a.x, fmaf(p.y, a.y, fmaf(p.z, a.z, fmaf(p.w, a.w, d))));
    }
    if (t >= 2) {
      float4 p = m2[lane + 64 * j];
      d2 = fmaf(p.x, a.x, fmaf(p.y, a.y, fmaf(p.z, a.z, fmaf(p.w, a.w, d2))));
    }
  }
  e = dpp_sum_reg(e);
  d = dpp_sum_reg(d);
  d2 = dpp_sum_reg(d2);
  if (lane == 63) scal4[b * T_STEPS + t] = make_float4(e, d, d2, 0.f);
}

// ---------------- sequential scan with pipelined scalar recurrence ----------------
// s_{i+1} = rinv_i*s_i + W_i ; n_{i+1} = rinv_i^2 n_i + 2 rinv_i b_i + e_i
// b_i = rinv_{i-1}*(G_i + d2_i) + d_i ; G_i = h_{i-2}.W_i (reduce issued 2 steps early)
__global__ __launch_bounds__(64) void scan_kernel(
    const float* __restrict__ h0,
    const float4* __restrict__ scal4,
    float* __restrict__ hreg) {
  const int b = blockIdx.x;
  const int lane = threadIdx.x;
  float4* h4 = (float4*)hreg;
  const int base = b * 256 + lane;
  const float4* sc_base = scal4 + b * T_STEPS;

  float4 s[4], hv[4], wx[6][4], sc[6];
  float greg[2];

  // standalone W[0], W[1]
  float4 w0[4], w1[4];
#pragma unroll
  for (int j = 0; j < 4; ++j) w0[j] = h4[(size_t)SLOT4C * 1 + base + 64 * j];
#pragma unroll
  for (int j = 0; j < 4; ++j) w1[j] = h4[(size_t)SLOT4C * 2 + base + 64 * j];
  // ring fill: W[2..7] -> slot (2+p)%6 (W[i] @ hreg slot i+1); scal[2..7]
#pragma unroll
  for (int p = 0; p < 6; ++p) {
#pragma unroll
    for (int j = 0; j < 4; ++j)
      wx[(2 + p) % 6][j] = h4[(size_t)SLOT4C * (3 + p) + base + 64 * j];
    sc[(2 + p) % 6] = sc_base[2 + p];
  }
  const float e1 = sc_base[1].x;

  // ---- step 0: s_1 = h_0 + W[0]; direct reduces for n_1, b_1; issue G_2 = h_0.W[2]
#pragma unroll
  for (int j = 0; j < 4; ++j) s[j] = ((const float4*)h0)[base + 64 * j];
#pragma unroll
  for (int j = 0; j < 4; ++j) h4[base + 64 * j] = s[j];  // slot 0 = h_0
  float4 s1[4];
  float q0 = 0, q1 = 0, q2 = 0, q3 = 0;
  float r0 = 0, r1 = 0, r2 = 0, r3 = 0;
  float u0 = 0, u1 = 0, u2 = 0, u3 = 0;
#pragma unroll
  for (int j = 0; j < 4; ++j) {
    s1[j].x = s[j].x + w0[j].x; s1[j].y = s[j].y + w0[j].y;
    s1[j].z = s[j].z + w0[j].z; s1[j].w = s[j].w + w0[j].w;
    q0 = fmaf(s1[j].x, s1[j].x, q0); q1 = fmaf(s1[j].y, s1[j].y, q1);
    q2 = fmaf(s1[j].z, s1[j].z, q2); q3 = fmaf(s1[j].w, s1[j].w, q3);
    r0 = fmaf(s1[j].x, w1[j].x, r0); r1 = fmaf(s1[j].y, w1[j].y, r1);
    r2 = fmaf(s1[j].z, w1[j].z, r2); r3 = fmaf(s1[j].w, w1[j].w, r3);
    u0 = fmaf(s[j].x, wx[2][j].x, u0); u1 = fmaf(s[j].y, wx[2][j].y, u1);
    u2 = fmaf(s[j].z, wx[2][j].z, u2); u3 = fmaf(s[j].w, wx[2][j].w, u3);
  }
  const float n1 = lane63(dpp_sum_reg((q0 + q1) + (q2 + q3)));
  const float b1 = lane63(dpp_sum_reg((r0 + r1) + (r2 + r3)));
  greg[0] = dpp_sum_reg((u0 + u1) + (u2 + u3));  // G_2 (parity 0)

  // ---- step 1: h_1, s_2, n_2; issue G_3 = h_1.W[3]
  float rinv = rsqrtf(fmaf(n1, 1.0f / DIM, EPSV));  // rinv_1
  float v0 = 0, v1 = 0, v2 = 0, v3 = 0;
#pragma unroll
  for (int j = 0; j < 4; ++j) {
    hv[j].x = rinv * s1[j].x; hv[j].y = rinv * s1[j].y;
    hv[j].z = rinv * s1[j].z; hv[j].w = rinv * s1[j].w;
  }
#pragma unroll
  for (int j = 0; j < 4; ++j) h4[(size_t)SLOT4C * 1 + base + 64 * j] = hv[j];
#pragma unroll
  for (int j = 0; j < 4; ++j) {
    s[j].x = hv[j].x + w1[j].x; s[j].y = hv[j].y + w1[j].y;
    s[j].z = hv[j].z + w1[j].z; s[j].w = hv[j].w + w1[j].w;
    v0 = fmaf(hv[j].x, wx[3][j].x, v0); v1 = fmaf(hv[j].y, wx[3][j].y, v1);
    v2 = fmaf(hv[j].z, wx[3][j].z, v2); v3 = fmaf(hv[j].w, wx[3][j].w, v3);
  }
  float n = fmaf(rinv, fmaf(rinv, n1, 2.0f * b1), e1);  // n_2
  greg[1] = dpp_sum_reg((v0 + v1) + (v2 + v3));         // G_3 (parity 1)
  float rinv_im1 = rinv;

  // ---- main loop i = 2..2047 (2046 = 341*6 iterations, static ring indices)
  for (int ii = 2; ii < T_STEPS; ii += 6) {
#pragma unroll
    for (int k = 0; k < 6; ++k) {
      const int i = ii + k;
      const int s0i = (2 + k) % 6;  // slot of W[i] / scal[i]
      const int s2i = (4 + k) % 6;  // slot of W[i+2]
      const int par = k & 1;
      // scalar stage
      const float rinv_i = rsqrtf(fmaf(n, 1.0f / DIM, EPSV));
      const float g = lane63(greg[par]);                           // G_i
      const float bb = fmaf(rinv_im1, g + sc[s0i].z, sc[s0i].y);   // b_i
      n = fmaf(rinv_i, fmaf(rinv_i, n, 2.0f * bb), sc[s0i].x);     // n_{i+1}
      // vector stage: h_i = rinv_i*s_i ; store ; s_{i+1} = h_i + W[i]
      float p0 = 0, p1 = 0, p2 = 0, p3 = 0;
#pragma unroll
      for (int j = 0; j < 4; ++j) {
        hv[j].x = rinv_i * s[j].x; hv[j].y = rinv_i * s[j].y;
        hv[j].z = rinv_i * s[j].z; hv[j].w = rinv_i * s[j].w;
      }
#pragma unroll
      for (int j = 0; j < 4; ++j)
        h4[(size_t)SLOT4C * i + base + 64 * j] = hv[j];
#pragma unroll
      for (int j = 0; j < 4; ++j) {
        s[j].x = hv[j].x + wx[s0i][j].x; s[j].y = hv[j].y + wx[s0i][j].y;
        s[j].z = hv[j].z + wx[s0i][j].z; s[j].w = hv[j].w + wx[s0i][j].w;
        p0 = fmaf(hv[j].x, wx[s2i][j].x, p0);
        p1 = fmaf(hv[j].y, wx[s2i][j].y, p1);
        p2 = fmaf(hv[j].z, wx[s2i][j].z, p2);
        p3 = fmaf(hv[j].w, wx[s2i][j].w, p3);
      }
      greg[par] = dpp_sum_reg((p0 + p1) + (p2 + p3));  // G_{i+2}
      // prefetch W[i+6], scal[i+6] into freed slot (clamped; tail values unused)
      const int ipf = (i + 6 < T_STEPS) ? (i + 6) : (T_STEPS - 1);
#pragma unroll
      for (int j = 0; j < 4; ++j)
        wx[s0i][j] = h4[(size_t)SLOT4C * (ipf + 1) + base + 64 * j];
      sc[s0i] = sc_base[ipf];
      rinv_im1 = rinv_i;
    }
  }
  // ---- final: h_T = rinv_T * s_T -> slot T
  const float rinv_T = rsqrtf(fmaf(n, 1.0f / DIM, EPSV));
#pragma unroll
  for (int j = 0; j < 4; ++j) {
    float4 o;
    o.x = rinv_T * s[j].x; o.y = rinv_T * s[j].y;
    o.z = rinv_T * s[j].z; o.w = rinv_T * s[j].w;
    h4[(size_t)SLOT4C * T_STEPS + base + 64 * j] = o;
  }
}

// ---------------- outs[t] = h_{t+1} * silu(h_{t+1}) ----------------
__global__ __launch_bounds__(256) void silu_kernel(const float4* __restrict__ hsrc,
                                                   float4* __restrict__ out4, int n4) {
  int i = blockIdx.x * blockDim.x + threadIdx.x;
  if (i >= n4) return;
  float4 h = hsrc[i];
  float4 o;
  o.x = h.x * h.x / (1.f + __expf(-h.x));
  o.y = h.y * h.y / (1.f + __expf(-h.y));
  o.z = h.z * h.z / (1.f + __expf(-h.z));
  o.w = h.w * h.w / (1.f + __expf(-h.w));
  out4[i] = o;
}

extern "C" void kernel_launch(void* const* d_in, const int* in_sizes, int n_in,
                              void* d_out, int out_size, void* d_ws, size_t ws_size,
                              hipStream_t stream) {
  (void)in_sizes; (void)n_in; (void)d_ws; (void)ws_size; (void)out_size;
  const float* x = (const float*)d_in[0];
  const float* h0 = (const float*)d_in[1];
  const float* W = (const float*)d_in[2];
  const float* bias = (const float*)d_in[3];
  const float* log_alpha = (const float*)d_in[4];

  float* out = (float*)d_out;                               // outs region [T][B][D]
  float* hreg = out + (size_t)T_STEPS * BATCH * DIM;        // h region [T+1][B][D]
  // staging overlays the outs region (consumed before scan/silu touch it)
  __hip_bfloat16* xb = (__hip_bfloat16*)d_out;
  __hip_bfloat16* wb = (__hip_bfloat16*)((char*)d_out + (size_t)T_STEPS * BATCH * DIM * 2);
  float4* scal4 = (float4*)(out + (size_t)26 * 1024 * 1024);  // 104 MB offset, 512 KB used

  const int nx8 = T_STEPS * BATCH * DIM / 8;
  const int nw8 = DIM * DIM / 8;
  cvt_kernel<<<nx8 / 256, 256, 0, stream>>>(x, (bf16x8pack*)xb, nx8);
  cvt_kernel<<<nw8 / 256, 256, 0, stream>>>(W, (bf16x8pack*)wb, nw8);

  dim3 ggrid(DIM / 128, (T_STEPS * BATCH) / 128);
  gemm_kernel<<<ggrid, 256, 0, stream>>>(xb, wb, bias, log_alpha, hreg);

  dots_kernel<<<T_STEPS * BATCH, 64, 0, stream>>>(hreg, scal4);

  scan_kernel<<<BATCH, 64, 0, stream>>>(h0, scal4, hreg);

  const int n4 = T_STEPS * BATCH * DIM / 4;
  silu_kernel<<<n4 / 256, 256, 0, stream>>>((const float4*)(hreg + BATCH * DIM),
                                            (float4*)out, n4);
}

// Round 4
// 609.321 us; speedup vs baseline: 1.2216x; 1.2216x over previous
//
#include <hip/hip_runtime.h>
#include <hip/hip_bf16.h>

#define T_STEPS 2048
#define BATCH 16
#define DIM 1024
#define EPSV 1e-6f
#define INVD (1.0f / 1024.0f)
#define SLOTF (BATCH * DIM)      // floats per [B][D] slot
#define SLOT4C (BATCH * DIM / 4) // float4 per slot

typedef short short8 __attribute__((ext_vector_type(8)));
typedef float f32x4 __attribute__((ext_vector_type(4)));

struct alignas(16) bf16x8pack { __hip_bfloat16 v[8]; };

// ---------------- fp32 -> bf16 convert (vectorized) ----------------
__global__ __launch_bounds__(256) void cvt_kernel(const float* __restrict__ src,
                                                  bf16x8pack* __restrict__ dst, int n8) {
  int i = blockIdx.x * blockDim.x + threadIdx.x;
  if (i >= n8) return;
  const float4* s4 = (const float4*)src + (size_t)i * 2;
  float4 a = s4[0];
  float4 b = s4[1];
  bf16x8pack p;
  p.v[0] = __float2bfloat16(a.x); p.v[1] = __float2bfloat16(a.y);
  p.v[2] = __float2bfloat16(a.z); p.v[3] = __float2bfloat16(a.w);
  p.v[4] = __float2bfloat16(b.x); p.v[5] = __float2bfloat16(b.y);
  p.v[6] = __float2bfloat16(b.z); p.v[7] = __float2bfloat16(b.w);
  dst[i] = p;
}

// ---------------- bf16 MFMA GEMM: out[m][e] = alpha*(sum_d X[m][d]*W[e][d] + b[e]) ----
__global__ __launch_bounds__(256) void gemm_kernel(
    const __hip_bfloat16* __restrict__ Xb,
    const __hip_bfloat16* __restrict__ Wb,
    const float* __restrict__ bias,
    const float* __restrict__ log_alpha_p,
    float* __restrict__ hreg) {
  __shared__ __hip_bfloat16 As[128 * 32];
  __shared__ __hip_bfloat16 Bs[128 * 32];
  const int tid = threadIdx.x;
  const int wave = tid >> 6, lane = tid & 63;
  const int m0 = blockIdx.y * 128;
  const int e0 = blockIdx.x * 128;
  const int wm = (wave >> 1) * 64;
  const int wn = (wave & 1) * 64;
  const int l15 = lane & 15, l4 = lane >> 4;

  f32x4 acc[4][4] = {};

  const int srow = wave * 16 + (lane >> 2);
  const int sch = (lane & 3) * 8;

  for (int kt = 0; kt < DIM; kt += 32) {
    __syncthreads();
#pragma unroll
    for (int i = 0; i < 2; ++i) {
      const __hip_bfloat16* ga = Xb + (size_t)(m0 + i * 64 + srow) * DIM + kt + sch;
      const __hip_bfloat16* gb = Wb + (size_t)(e0 + i * 64 + srow) * DIM + kt + sch;
      __builtin_amdgcn_global_load_lds(
          (const __attribute__((address_space(1))) void*)ga,
          (__attribute__((address_space(3))) void*)((char*)As + (i * 64 + wave * 16) * 64),
          16, 0, 0);
      __builtin_amdgcn_global_load_lds(
          (const __attribute__((address_space(1))) void*)gb,
          (__attribute__((address_space(3))) void*)((char*)Bs + (i * 64 + wave * 16) * 64),
          16, 0, 0);
    }
    __syncthreads();
    short8 a[4], b[4];
#pragma unroll
    for (int f = 0; f < 4; ++f)
      a[f] = *(const short8*)((const char*)As + ((wm + f * 16 + l15) * 32 + l4 * 8) * 2);
#pragma unroll
    for (int g = 0; g < 4; ++g)
      b[g] = *(const short8*)((const char*)Bs + ((wn + g * 16 + l15) * 32 + l4 * 8) * 2);
#pragma unroll
    for (int f = 0; f < 4; ++f)
#pragma unroll
      for (int g = 0; g < 4; ++g)
        acc[f][g] = __builtin_amdgcn_mfma_f32_16x16x32_bf16(a[f], b[g], acc[f][g], 0, 0, 0);
  }
  const float alpha = __expf(log_alpha_p[0]);
#pragma unroll
  for (int g = 0; g < 4; ++g) {
    const int e = e0 + wn + g * 16 + l15;
    const float bv = bias[e];
#pragma unroll
    for (int f = 0; f < 4; ++f) {
#pragma unroll
      for (int r = 0; r < 4; ++r) {
        const int m = m0 + wm + f * 16 + l4 * 4 + r;
        hreg[(size_t)(m + BATCH) * DIM + e] = alpha * (acc[f][g][r] + bv);
      }
    }
  }
}

// ---------------- DPP wave-sum helper (total lands in lane 63) ----------------
__device__ __forceinline__ float dpp_sum_reg(float x) {
  float acc = x;
#define DPP_ADD(ctrl)                                                              \
  {                                                                                \
    int t_ = __builtin_amdgcn_update_dpp(0, __float_as_int(acc), (ctrl), 0xf, 0xf, \
                                         true);                                    \
    acc += __int_as_float(t_);                                                     \
  }
  DPP_ADD(0x111); DPP_ADD(0x112); DPP_ADD(0x114); DPP_ADD(0x118);
  DPP_ADD(0x142); DPP_ADD(0x143);
#undef DPP_ADD
  return acc;
}

// ---- precompute e=||W_t||^2, d=W_{t-1}.W_t, d2=W_{t-2}.W_t, d3=W_{t-3}.W_t ----
__global__ __launch_bounds__(64) void dots_kernel(const float* __restrict__ hreg,
                                                  float4* __restrict__ scal4) {
  const int t = blockIdx.x >> 4;
  const int b = blockIdx.x & 15;
  const int lane = threadIdx.x;
  const float4* w  = (const float4*)(hreg + (size_t)(t + 1) * SLOTF + b * DIM);
  const float4* m1 = (const float4*)(hreg + (size_t)(t    ) * SLOTF + b * DIM);
  const float4* m2 = (const float4*)(hreg + (size_t)(t - 1) * SLOTF + b * DIM);
  const float4* m3 = (const float4*)(hreg + (size_t)(t - 2) * SLOTF + b * DIM);
  float e = 0.f, d = 0.f, d2 = 0.f, d3 = 0.f;
#pragma unroll
  for (int j = 0; j < 4; ++j) {
    float4 a = w[lane + 64 * j];
    e = fmaf(a.x, a.x, fmaf(a.y, a.y, fmaf(a.z, a.z, fmaf(a.w, a.w, e))));
    if (t >= 1) {
      float4 p = m1[lane + 64 * j];
      d = fmaf(p.x, a.x, fmaf(p.y, a.y, fmaf(p.z, a.z, fmaf(p.w, a.w, d))));
    }
    if (t >= 2) {
      float4 p = m2[lane + 64 * j];
      d2 = fmaf(p.x, a.x, fmaf(p.y, a.y, fmaf(p.z, a.z, fmaf(p.w, a.w, d2))));
    }
    if (t >= 3) {
      float4 p = m3[lane + 64 * j];
      d3 = fmaf(p.x, a.x, fmaf(p.y, a.y, fmaf(p.z, a.z, fmaf(p.w, a.w, d3))));
    }
  }
  e = dpp_sum_reg(e);
  d = dpp_sum_reg(d);
  d2 = dpp_sum_reg(d2);
  d3 = dpp_sum_reg(d3);
  if (lane == 63) scal4[b * T_STEPS + t] = make_float4(e, d, d2, d3);
}

// ---------------- sequential scan, 4 waves per batch row ----------------
// s_{i+1} = rinv_i*s_i + W_i ; n_{i+1} = rinv_i^2 n_i + 2 rinv_i b_i + e_i
// b_i = d_i + r_{i-1} d2_i + r_{i-1} r_{i-2} (d3_i + G_i), G_i = h_{i-3}.W_i.
// Per step: per-wave DPP partial of h_i.W_{i+3} -> LDS; combined next step;
// used 2 steps later. Raw s_barrier + lgkmcnt-only drain (no vmcnt(0)!) keeps
// the 8-deep W prefetch ring in flight across barriers.
__global__ __launch_bounds__(256) void scan_kernel(
    const float* __restrict__ h0,
    const float4* __restrict__ scal4,
    float* __restrict__ hreg) {
  const int b = blockIdx.x;
  const int tid = threadIdx.x;
  const int wave = tid >> 6;
  const int lane = tid & 63;
  float4* h4 = (float4*)hreg;
  const int idx4 = b * 256 + tid;  // this thread's float4 within a [B][D] slot

  __shared__ float4 scLDS[T_STEPS];  // 32 KB: scal row for this batch
  __shared__ float Gp[4][4];         // [ring slot][wave] partial sums
  __shared__ float initP[4][8];      // edge partials

  // stage scal row into LDS
#pragma unroll
  for (int p = 0; p < 8; ++p)
    scLDS[p * 256 + tid] = scal4[b * T_STEPS + p * 256 + tid];

  // W ring fill: w[i&7] = W[i] for i=2..9 (W[i] lives at hreg slot i+1)
  float4 w[8];
  w[2] = h4[(size_t)SLOT4C * 3 + idx4];
  w[3] = h4[(size_t)SLOT4C * 4 + idx4];
  w[4] = h4[(size_t)SLOT4C * 5 + idx4];
  w[5] = h4[(size_t)SLOT4C * 6 + idx4];
  w[6] = h4[(size_t)SLOT4C * 7 + idx4];
  w[7] = h4[(size_t)SLOT4C * 8 + idx4];
  w[0] = h4[(size_t)SLOT4C * 9 + idx4];   // W[8]
  w[1] = h4[(size_t)SLOT4C * 10 + idx4];  // W[9]
  float4 w0v = h4[(size_t)SLOT4C * 1 + idx4];  // W[0]
  float4 w1v = h4[(size_t)SLOT4C * 2 + idx4];  // W[1]
  float4 h0v = ((const float4*)h0)[idx4];
  h4[idx4] = h0v;  // slot 0 = h_0

  // ---- edge: s_1 = h_0 + W[0]; direct reduces n1, b1=s1.W1, c2=s1.W2,
  //            G3=h0.W3, c4=s1.W4
  float4 s;
  s.x = h0v.x + w0v.x; s.y = h0v.y + w0v.y;
  s.z = h0v.z + w0v.z; s.w = h0v.w + w0v.w;
  float q  = fmaf(s.x, s.x, fmaf(s.y, s.y, fmaf(s.z, s.z, s.w * s.w)));
  float r  = fmaf(s.x, w1v.x, fmaf(s.y, w1v.y, fmaf(s.z, w1v.z, s.w * w1v.w)));
  float u2 = fmaf(s.x, w[2].x, fmaf(s.y, w[2].y, fmaf(s.z, w[2].z, s.w * w[2].w)));
  float g3 = fmaf(h0v.x, w[3].x, fmaf(h0v.y, w[3].y, fmaf(h0v.z, w[3].z, h0v.w * w[3].w)));
  float u4 = fmaf(s.x, w[4].x, fmaf(s.y, w[4].y, fmaf(s.z, w[4].z, s.w * w[4].w)));
  q = dpp_sum_reg(q); r = dpp_sum_reg(r); u2 = dpp_sum_reg(u2);
  g3 = dpp_sum_reg(g3); u4 = dpp_sum_reg(u4);
  if (lane == 63) {
    initP[wave][0] = q; initP[wave][1] = r; initP[wave][2] = u2;
    initP[wave][3] = g3; initP[wave][4] = u4;
  }
  __syncthreads();
  const float n1  = initP[0][0] + initP[1][0] + initP[2][0] + initP[3][0];
  const float b1  = initP[0][1] + initP[1][1] + initP[2][1] + initP[3][1];
  const float c2  = initP[0][2] + initP[1][2] + initP[2][2] + initP[3][2];
  const float G3v = initP[0][3] + initP[1][3] + initP[2][3] + initP[3][3];
  const float c4  = initP[0][4] + initP[1][4] + initP[2][4] + initP[3][4];

  float4 sc0 = scLDS[2];  // scal[2] (used at step 2)
  float4 sc1 = scLDS[3];  // scal[3] (used at step 3)
  const float e1 = scLDS[1].x;

  const float rinv1 = rsqrtf(fmaf(n1, INVD, EPSV));
  float n = fmaf(rinv1, fmaf(rinv1, n1, 2.0f * b1), e1);  // n_2
  const float b2p = fmaf(rinv1, c2, sc0.y);               // b'_2 = rinv1*c2 + d_2
  float gr1 = G3v;          // G_3  (used at step 3: parity 1)
  float gr0 = rinv1 * c4;   // G_4  (used at step 4: parity 0)

  // ---- step 1: h_1 = rinv1*s_1 -> slot 1 ; s_2 = h_1 + W[1]
  {
    float4 hv;
    hv.x = rinv1 * s.x; hv.y = rinv1 * s.y; hv.z = rinv1 * s.z; hv.w = rinv1 * s.w;
    h4[(size_t)SLOT4C * 1 + idx4] = hv;
    s.x = hv.x + w1v.x; s.y = hv.y + w1v.y; s.z = hv.z + w1v.z; s.w = hv.w + w1v.w;
  }
  float rm1 = rinv1, rm2 = 0.0f;

// MODE: 0 normal; 1 = bb from b2p, no combine; 2 = formula bb, no combine.
#define STEP(IEXPR, WS, W3S, SCA, GPW, GPR, GRW, GRU, MODE)                          \
  {                                                                                  \
    const int i_ = (IEXPR);                                                          \
    const float rinv = rsqrtf(fmaf(n, INVD, EPSV));                                  \
    float bb;                                                                        \
    if ((MODE) == 1) bb = b2p;                                                       \
    else bb = fmaf(rm1, fmaf(rm2, SCA.w + GRU, SCA.z), SCA.y);                       \
    n = fmaf(rinv, fmaf(rinv, n, 2.0f * bb), SCA.x);                                 \
    float4 hv_;                                                                      \
    hv_.x = rinv * s.x; hv_.y = rinv * s.y;                                          \
    hv_.z = rinv * s.z; hv_.w = rinv * s.w;                                          \
    h4[(size_t)SLOT4C * i_ + idx4] = hv_;                                            \
    s.x = hv_.x + w[WS].x; s.y = hv_.y + w[WS].y;                                    \
    s.z = hv_.z + w[WS].z; s.w = hv_.w + w[WS].w;                                    \
    float p_ = fmaf(hv_.x, w[W3S].x, fmaf(hv_.y, w[W3S].y,                           \
               fmaf(hv_.z, w[W3S].z, hv_.w * w[W3S].w)));                            \
    p_ = dpp_sum_reg(p_);                                                            \
    if (lane == 63) Gp[GPW][wave] = p_;                                              \
    if ((MODE) == 0) {                                                               \
      float4 g4_ = *(const float4*)&Gp[GPR][0];                                      \
      GRW = (g4_.x + g4_.y) + (g4_.z + g4_.w);                                       \
    }                                                                                \
    const int ipf_ = (i_ + 8 < T_STEPS) ? i_ + 8 : T_STEPS - 1;                      \
    w[WS] = h4[(size_t)SLOT4C * (ipf_ + 1) + idx4];                                  \
    const int isc_ = (i_ + 2 < T_STEPS) ? i_ + 2 : T_STEPS - 1;                      \
    SCA = scLDS[isc_];                                                               \
    rm2 = rm1; rm1 = rinv;                                                           \
    asm volatile("s_waitcnt lgkmcnt(0)" ::: "memory");                               \
    __builtin_amdgcn_sched_barrier(0);                                               \
    __builtin_amdgcn_s_barrier();                                                    \
  }

  // peeled steps 2,3,4
  STEP(2, 2, 5, sc0, 2, 0, gr0, gr1, 1)
  STEP(3, 3, 6, sc1, 3, 0, gr0, gr1, 2)
  STEP(4, 4, 7, sc0, 0, 2, gr1, gr0, 0)

  // main loop: i = 5..2044 (255 chunks of 8)
  for (int ii = 5; ii <= 2037; ii += 8) {
    STEP(ii + 0, 5, 0, sc1, 1, 3, gr0, gr1, 0)
    STEP(ii + 1, 6, 1, sc0, 2, 0, gr1, gr0, 0)
    STEP(ii + 2, 7, 2, sc1, 3, 1, gr0, gr1, 0)
    STEP(ii + 3, 0, 3, sc0, 0, 2, gr1, gr0, 0)
    STEP(ii + 4, 1, 4, sc1, 1, 3, gr0, gr1, 0)
    STEP(ii + 5, 2, 5, sc0, 2, 0, gr1, gr0, 0)
    STEP(ii + 6, 3, 6, sc1, 3, 1, gr0, gr1, 0)
    STEP(ii + 7, 4, 7, sc0, 0, 2, gr1, gr0, 0)
  }
  // tail: i = 2045, 2046, 2047
  STEP(2045, 5, 0, sc1, 1, 3, gr0, gr1, 0)
  STEP(2046, 6, 1, sc0, 2, 0, gr1, gr0, 0)
  STEP(2047, 7, 2, sc1, 3, 1, gr0, gr1, 0)
#undef STEP

  // final: h_2048 = rinv_2048 * s_2048 -> slot 2048
  const float rinvT = rsqrtf(fmaf(n, INVD, EPSV));
  float4 o;
  o.x = rinvT * s.x; o.y = rinvT * s.y; o.z = rinvT * s.z; o.w = rinvT * s.w;
  h4[(size_t)SLOT4C * T_STEPS + idx4] = o;
}

// ---------------- outs[t] = h_{t+1} * silu(h_{t+1}) ----------------
__global__ __launch_bounds__(256) void silu_kernel(const float4* __restrict__ hsrc,
                                                   float4* __restrict__ out4, int n4) {
  int i = blockIdx.x * blockDim.x + threadIdx.x;
  if (i >= n4) return;
  float4 h = hsrc[i];
  float4 o;
  o.x = h.x * h.x / (1.f + __expf(-h.x));
  o.y = h.y * h.y / (1.f + __expf(-h.y));
  o.z = h.z * h.z / (1.f + __expf(-h.z));
  o.w = h.w * h.w / (1.f + __expf(-h.w));
  out4[i] = o;
}

extern "C" void kernel_launch(void* const* d_in, const int* in_sizes, int n_in,
                              void* d_out, int out_size, void* d_ws, size_t ws_size,
                              hipStream_t stream) {
  (void)in_sizes; (void)n_in; (void)d_ws; (void)ws_size; (void)out_size;
  const float* x = (const float*)d_in[0];
  const float* h0 = (const float*)d_in[1];
  const float* W = (const float*)d_in[2];
  const float* bias = (const float*)d_in[3];
  const float* log_alpha = (const float*)d_in[4];

  float* out = (float*)d_out;                               // outs region [T][B][D]
  float* hreg = out + (size_t)T_STEPS * BATCH * DIM;        // h region [T+1][B][D]
  // staging overlays the outs region (consumed before scan/silu touch it)
  __hip_bfloat16* xb = (__hip_bfloat16*)d_out;
  __hip_bfloat16* wb = (__hip_bfloat16*)((char*)d_out + (size_t)T_STEPS * BATCH * DIM * 2);
  float4* scal4 = (float4*)(out + (size_t)26 * 1024 * 1024);  // 104 MB offset, 512 KB used

  const int nx8 = T_STEPS * BATCH * DIM / 8;
  const int nw8 = DIM * DIM / 8;
  cvt_kernel<<<nx8 / 256, 256, 0, stream>>>(x, (bf16x8pack*)xb, nx8);
  cvt_kernel<<<nw8 / 256, 256, 0, stream>>>(W, (bf16x8pack*)wb, nw8);

  dim3 ggrid(DIM / 128, (T_STEPS * BATCH) / 128);
  gemm_kernel<<<ggrid, 256, 0, stream>>>(xb, wb, bias, log_alpha, hreg);

  dots_kernel<<<T_STEPS * BATCH, 64, 0, stream>>>(hreg, scal4);

  scan_kernel<<<BATCH, 256, 0, stream>>>(h0, scal4, hreg);

  const int n4 = T_STEPS * BATCH * DIM / 4;
  silu_kernel<<<n4 / 256, 256, 0, stream>>>((const float4*)(hreg + BATCH * DIM),
                                            (float4*)out, n4);
}

// Round 5
// 592.387 us; speedup vs baseline: 1.2565x; 1.0286x over previous
//
#include <hip/hip_runtime.h>
#include <hip/hip_bf16.h>

#define T_STEPS 2048
#define BATCH 16
#define DIM 1024
#define EPSV 1e-6f
#define INVD (1.0f / 1024.0f)
#define SLOTF (BATCH * DIM)      // floats per [B][D] slot
#define SLOT4C (BATCH * DIM / 4) // float4 per slot

typedef short short8 __attribute__((ext_vector_type(8)));
typedef float f32x4 __attribute__((ext_vector_type(4)));

struct alignas(16) bf16x8pack { __hip_bfloat16 v[8]; };

__device__ __forceinline__ float dot4(const float4& a, const float4& c) {
  return fmaf(a.x, c.x, fmaf(a.y, c.y, fmaf(a.z, c.z, a.w * c.w)));
}

// ---------------- fp32 -> bf16 convert (vectorized) ----------------
__global__ __launch_bounds__(256) void cvt_kernel(const float* __restrict__ src,
                                                  bf16x8pack* __restrict__ dst, int n8) {
  int i = blockIdx.x * blockDim.x + threadIdx.x;
  if (i >= n8) return;
  const float4* s4 = (const float4*)src + (size_t)i * 2;
  float4 a = s4[0];
  float4 b = s4[1];
  bf16x8pack p;
  p.v[0] = __float2bfloat16(a.x); p.v[1] = __float2bfloat16(a.y);
  p.v[2] = __float2bfloat16(a.z); p.v[3] = __float2bfloat16(a.w);
  p.v[4] = __float2bfloat16(b.x); p.v[5] = __float2bfloat16(b.y);
  p.v[6] = __float2bfloat16(b.z); p.v[7] = __float2bfloat16(b.w);
  dst[i] = p;
}

// ---------------- bf16 MFMA GEMM: out[m][e] = alpha*(sum_d X[m][d]*W[e][d] + b[e]) ----
__global__ __launch_bounds__(256) void gemm_kernel(
    const __hip_bfloat16* __restrict__ Xb,
    const __hip_bfloat16* __restrict__ Wb,
    const float* __restrict__ bias,
    const float* __restrict__ log_alpha_p,
    float* __restrict__ hreg) {
  __shared__ __hip_bfloat16 As[128 * 32];
  __shared__ __hip_bfloat16 Bs[128 * 32];
  const int tid = threadIdx.x;
  const int wave = tid >> 6, lane = tid & 63;
  const int m0 = blockIdx.y * 128;
  const int e0 = blockIdx.x * 128;
  const int wm = (wave >> 1) * 64;
  const int wn = (wave & 1) * 64;
  const int l15 = lane & 15, l4 = lane >> 4;

  f32x4 acc[4][4] = {};

  const int srow = wave * 16 + (lane >> 2);
  const int sch = (lane & 3) * 8;

  for (int kt = 0; kt < DIM; kt += 32) {
    __syncthreads();
#pragma unroll
    for (int i = 0; i < 2; ++i) {
      const __hip_bfloat16* ga = Xb + (size_t)(m0 + i * 64 + srow) * DIM + kt + sch;
      const __hip_bfloat16* gb = Wb + (size_t)(e0 + i * 64 + srow) * DIM + kt + sch;
      __builtin_amdgcn_global_load_lds(
          (const __attribute__((address_space(1))) void*)ga,
          (__attribute__((address_space(3))) void*)((char*)As + (i * 64 + wave * 16) * 64),
          16, 0, 0);
      __builtin_amdgcn_global_load_lds(
          (const __attribute__((address_space(1))) void*)gb,
          (__attribute__((address_space(3))) void*)((char*)Bs + (i * 64 + wave * 16) * 64),
          16, 0, 0);
    }
    __syncthreads();
    short8 a[4], b[4];
#pragma unroll
    for (int f = 0; f < 4; ++f)
      a[f] = *(const short8*)((const char*)As + ((wm + f * 16 + l15) * 32 + l4 * 8) * 2);
#pragma unroll
    for (int g = 0; g < 4; ++g)
      b[g] = *(const short8*)((const char*)Bs + ((wn + g * 16 + l15) * 32 + l4 * 8) * 2);
#pragma unroll
    for (int f = 0; f < 4; ++f)
#pragma unroll
      for (int g = 0; g < 4; ++g)
        acc[f][g] = __builtin_amdgcn_mfma_f32_16x16x32_bf16(a[f], b[g], acc[f][g], 0, 0, 0);
  }
  const float alpha = __expf(log_alpha_p[0]);
#pragma unroll
  for (int g = 0; g < 4; ++g) {
    const int e = e0 + wn + g * 16 + l15;
    const float bv = bias[e];
#pragma unroll
    for (int f = 0; f < 4; ++f) {
#pragma unroll
      for (int r = 0; r < 4; ++r) {
        const int m = m0 + wm + f * 16 + l4 * 4 + r;
        hreg[(size_t)(m + BATCH) * DIM + e] = alpha * (acc[f][g][r] + bv);
      }
    }
  }
}

// ---------------- DPP wave-sum helper (total lands in lane 63) ----------------
__device__ __forceinline__ float dpp_sum_reg(float x) {
  float acc = x;
#define DPP_ADD(ctrl)                                                              \
  {                                                                                \
    int t_ = __builtin_amdgcn_update_dpp(0, __float_as_int(acc), (ctrl), 0xf, 0xf, \
                                         true);                                    \
    acc += __int_as_float(t_);                                                     \
  }
  DPP_ADD(0x111); DPP_ADD(0x112); DPP_ADD(0x114); DPP_ADD(0x118);
  DPP_ADD(0x142); DPP_ADD(0x143);
#undef DPP_ADD
  return acc;
}

// ---- precompute: scal4[t]=(e, 2d, 2d2, 2d3), d4g[t]=2*d4  (d_k = W_{t-k}.W_t) ----
__global__ __launch_bounds__(64) void dots_kernel(const float* __restrict__ hreg,
                                                  float4* __restrict__ scal4,
                                                  float* __restrict__ d4g) {
  const int t = blockIdx.x >> 4;
  const int b = blockIdx.x & 15;
  const int lane = threadIdx.x;
  const float4* w  = (const float4*)(hreg + (size_t)(t + 1) * SLOTF + b * DIM);
  const float4* m1 = (const float4*)(hreg + (size_t)(t    ) * SLOTF + b * DIM);
  const float4* m2 = (const float4*)(hreg + (size_t)(t - 1) * SLOTF + b * DIM);
  const float4* m3 = (const float4*)(hreg + (size_t)(t - 2) * SLOTF + b * DIM);
  const float4* m4 = (const float4*)(hreg + (size_t)(t - 3) * SLOTF + b * DIM);
  float e = 0.f, d = 0.f, d2 = 0.f, d3 = 0.f, d4 = 0.f;
#pragma unroll
  for (int j = 0; j < 4; ++j) {
    float4 a = w[lane + 64 * j];
    e = fmaf(a.x, a.x, fmaf(a.y, a.y, fmaf(a.z, a.z, fmaf(a.w, a.w, e))));
    if (t >= 1) { float4 p = m1[lane + 64 * j];
      d = fmaf(p.x, a.x, fmaf(p.y, a.y, fmaf(p.z, a.z, fmaf(p.w, a.w, d)))); }
    if (t >= 2) { float4 p = m2[lane + 64 * j];
      d2 = fmaf(p.x, a.x, fmaf(p.y, a.y, fmaf(p.z, a.z, fmaf(p.w, a.w, d2)))); }
    if (t >= 3) { float4 p = m3[lane + 64 * j];
      d3 = fmaf(p.x, a.x, fmaf(p.y, a.y, fmaf(p.z, a.z, fmaf(p.w, a.w, d3)))); }
    if (t >= 4) { float4 p = m4[lane + 64 * j];
      d4 = fmaf(p.x, a.x, fmaf(p.y, a.y, fmaf(p.z, a.z, fmaf(p.w, a.w, d4)))); }
  }
  e = dpp_sum_reg(e);
  d = dpp_sum_reg(d);
  d2 = dpp_sum_reg(d2);
  d3 = dpp_sum_reg(d3);
  d4 = dpp_sum_reg(d4);
  if (lane == 63) {
    scal4[b * T_STEPS + t] = make_float4(e, d + d, d2 + d2, d3 + d3);
    d4g[b * T_STEPS + t] = d4 + d4;
  }
}

// ---------------- sequential scan, 4 waves per batch row, depth-4 pipeline --------
// s_{i+1}=h_i+W_i, h_i=rinv_i*s_i, n_{i+1}=rinv^2 n + 2 rinv b_i + e_i,
// 2b_i = 2d_i + r1(2d2_i + r2(2d3_i + r3(2d4_i + 2G_i))), G_i=h_{i-4}.W_i.
// G pipeline: partial@i (DPP) -> ds_write @i+1 START -> read @i+2 -> combine @i+3
// -> use @i+4.  End-of-step wait = counted lgkmcnt(3) (confirms only the write;
// reads keep slack; global W-ring never drained).
__global__ __launch_bounds__(256) void scan_kernel(
    const float* __restrict__ h0,
    const float4* __restrict__ scal4,
    const float* __restrict__ d4g,
    float* __restrict__ hreg) {
  const int b = blockIdx.x;
  const int tid = threadIdx.x;
  const int wave = tid >> 6;
  const int lane = tid & 63;
  float4* h4 = (float4*)hreg;
  const int idx4 = b * 256 + tid;

  __shared__ float4 scLDS[T_STEPS];          // 32 KB
  __shared__ float d4LDS[T_STEPS];           // 8 KB
  __shared__ alignas(16) float Gp[4][4];     // [compute-step&3][wave]
  __shared__ float initP[4][8];

  // stage scal/d4 rows for this batch
#pragma unroll
  for (int p = 0; p < 8; ++p)
    scLDS[p * 256 + tid] = scal4[b * T_STEPS + p * 256 + tid];
#pragma unroll
  for (int p = 0; p < 8; ++p)
    d4LDS[p * 256 + tid] = d4g[b * T_STEPS + p * 256 + tid];

  // W ring: w[k&7] = W_k for k=2..9 (W_k at hreg slot k+1)
  float4 w[8];
  w[2] = h4[(size_t)SLOT4C * 3 + idx4];
  w[3] = h4[(size_t)SLOT4C * 4 + idx4];
  w[4] = h4[(size_t)SLOT4C * 5 + idx4];
  w[5] = h4[(size_t)SLOT4C * 6 + idx4];
  w[6] = h4[(size_t)SLOT4C * 7 + idx4];
  w[7] = h4[(size_t)SLOT4C * 8 + idx4];
  w[0] = h4[(size_t)SLOT4C * 9 + idx4];
  w[1] = h4[(size_t)SLOT4C * 10 + idx4];
  float4 w0v = h4[(size_t)SLOT4C * 1 + idx4];
  float4 w1v = h4[(size_t)SLOT4C * 2 + idx4];
  float4 h0v = ((const float4*)h0)[idx4];
  h4[idx4] = h0v;  // slot 0 = h_0

  // startup direct reductions: n1=||s1||^2, b1=s1.W1, c2=s1.W2, c3=s1.W3, g4=h0.W4
  float4 s;
  s.x = h0v.x + w0v.x; s.y = h0v.y + w0v.y;
  s.z = h0v.z + w0v.z; s.w = h0v.w + w0v.w;
  float q = dpp_sum_reg(dot4(s, s));
  float r = dpp_sum_reg(dot4(s, w1v));
  float u2 = dpp_sum_reg(dot4(s, w[2]));
  float u3 = dpp_sum_reg(dot4(s, w[3]));
  float g4 = dpp_sum_reg(dot4(h0v, w[4]));
  if (lane == 63) {
    initP[wave][0] = q; initP[wave][1] = r; initP[wave][2] = u2;
    initP[wave][3] = g4; initP[wave][4] = u3;
  }
  __syncthreads();
  const float n1 = (initP[0][0] + initP[1][0]) + (initP[2][0] + initP[3][0]);
  float bs = (initP[0][1] + initP[1][1]) + (initP[2][1] + initP[3][1]);
  float c2s = (initP[0][2] + initP[1][2]) + (initP[2][2] + initP[3][2]);
  float g4s = (initP[0][3] + initP[1][3]) + (initP[2][3] + initP[3][3]);
  float c3s = (initP[0][4] + initP[1][4]) + (initP[2][4] + initP[3][4]);
  const float B1 = bs + bs;
  const float C2 = c2s + c2s;
  const float C3 = c3s + c3s;
  float gr0 = g4s + g4s;  // 2*G_4 (used step 4)
  float gr1 = 0.0f;       // filled at step 4 (2*G_5)

  const float e1 = scLDS[1].x;
  float4 sc2 = scLDS[2], sc3 = scLDS[3];
  float4 scA = scLDS[4], scB = scLDS[5];
  float d4A = d4LDS[4], d4B = d4LDS[5];
  float4 rv = make_float4(0.f, 0.f, 0.f, 0.f);
  float n = n1, rm1, rm2, rm3, pp;

  // ---- step 1: n2; h1; s2; pp = partial G_5
  {
    const float rinv = rsqrtf(fmaf(n, INVD, EPSV));
    n = fmaf(rinv, fmaf(rinv, n, B1), e1);
    float4 hv;
    hv.x = rinv * s.x; hv.y = rinv * s.y; hv.z = rinv * s.z; hv.w = rinv * s.w;
    h4[(size_t)SLOT4C * 1 + idx4] = hv;
    s.x = hv.x + w1v.x; s.y = hv.y + w1v.y; s.z = hv.z + w1v.z; s.w = hv.w + w1v.w;
    pp = dpp_sum_reg(dot4(hv, w[5]));
    rm1 = rinv;
    asm volatile("s_waitcnt lgkmcnt(0)" ::: "memory");
    __builtin_amdgcn_s_barrier();
  }
  // ---- step 2: write G_5 partial; n3; pp = G_6 partial
  {
    if (lane == 63) Gp[1][wave] = pp;
    const float rinv = rsqrtf(fmaf(n, INVD, EPSV));
    const float BB = fmaf(rm1, C2, sc2.y);
    n = fmaf(rinv, fmaf(rinv, n, BB), sc2.x);
    float4 hv;
    hv.x = rinv * s.x; hv.y = rinv * s.y; hv.z = rinv * s.z; hv.w = rinv * s.w;
    h4[(size_t)SLOT4C * 2 + idx4] = hv;
    s.x = hv.x + w[2].x; s.y = hv.y + w[2].y; s.z = hv.z + w[2].z; s.w = hv.w + w[2].w;
    pp = dpp_sum_reg(dot4(hv, w[6]));
    w[2] = h4[(size_t)SLOT4C * 11 + idx4];  // W_10
    rm2 = rm1; rm1 = rinv;
    asm volatile("s_waitcnt lgkmcnt(0)" ::: "memory");
    __builtin_amdgcn_s_barrier();
  }
  // ---- step 3: write G_6 partial; read G_5 partials; n4; pp = G_7 partial
  {
    if (lane == 63) Gp[2][wave] = pp;
    const float rinv = rsqrtf(fmaf(n, INVD, EPSV));
    const float BB = fmaf(rm1, fmaf(rm2, C3, sc3.z), sc3.y);
    n = fmaf(rinv, fmaf(rinv, n, BB), sc3.x);
    rv = *(const float4*)&Gp[1][0];
    float4 hv;
    hv.x = rinv * s.x; hv.y = rinv * s.y; hv.z = rinv * s.z; hv.w = rinv * s.w;
    h4[(size_t)SLOT4C * 3 + idx4] = hv;
    s.x = hv.x + w[3].x; s.y = hv.y + w[3].y; s.z = hv.z + w[3].z; s.w = hv.w + w[3].w;
    pp = dpp_sum_reg(dot4(hv, w[7]));
    w[3] = h4[(size_t)SLOT4C * 12 + idx4];  // W_11
    rm3 = rm2; rm2 = rm1; rm1 = rinv;
    asm volatile("s_waitcnt lgkmcnt(0)" ::: "memory");
    __builtin_amdgcn_s_barrier();
  }

// Steady step i (i>=4). DS order: write(prev pp) | rv read | sc read | d4 read.
// GW=(i-1)&3, GR=(i-2)&3. GRU = gr[i&1] (2*G_i), GRW = gr[(i+1)&1] (gets 2*G_{i+1}).
#define STEP(I_, WS, W4S, GW, GR, SC, D4R, GRU, GRW)                                 \
  {                                                                                  \
    const int i_ = (I_);                                                             \
    if (lane == 63) Gp[GW][wave] = pp;                                               \
    asm volatile("" ::: "memory");                                                   \
    const float rinv = rsqrtf(fmaf(n, INVD, EPSV));                                  \
    const float BB =                                                                 \
        fmaf(rm1, fmaf(rm2, fmaf(rm3, (D4R) + (GRU), (SC).w), (SC).z), (SC).y);      \
    n = fmaf(rinv, fmaf(rinv, n, BB), (SC).x);                                       \
    {                                                                                \
      float gt_ = (rv.x + rv.y) + (rv.z + rv.w);                                     \
      GRW = gt_ + gt_;                                                               \
    }                                                                                \
    rv = *(const float4*)&Gp[GR][0];                                                 \
    const int isc_ = (i_ + 2 < T_STEPS) ? (i_ + 2) : (T_STEPS - 1);                  \
    SC = scLDS[isc_];                                                                \
    D4R = d4LDS[isc_];                                                               \
    float4 hv_;                                                                      \
    hv_.x = rinv * s.x; hv_.y = rinv * s.y;                                          \
    hv_.z = rinv * s.z; hv_.w = rinv * s.w;                                          \
    h4[(size_t)SLOT4C * i_ + idx4] = hv_;                                            \
    s.x = hv_.x + w[WS].x; s.y = hv_.y + w[WS].y;                                    \
    s.z = hv_.z + w[WS].z; s.w = hv_.w + w[WS].w;                                    \
    pp = dpp_sum_reg(dot4(hv_, w[W4S]));                                             \
    const int ipf_ = (i_ + 8 < T_STEPS) ? (i_ + 8) : (T_STEPS - 1);                  \
    w[WS] = h4[(size_t)SLOT4C * (ipf_ + 1) + idx4];                                  \
    rm3 = rm2; rm2 = rm1; rm1 = rinv;                                                \
    asm volatile("s_waitcnt lgkmcnt(3)" ::: "memory");                               \
    __builtin_amdgcn_s_barrier();                                                    \
  }

  // main loop: i = 4..2043 (255 chunks of 8)
  for (int ii = 4; ii <= 2036; ii += 8) {
    STEP(ii + 0, 4, 0, 3, 2, scA, d4A, gr0, gr1)
    STEP(ii + 1, 5, 1, 0, 3, scB, d4B, gr1, gr0)
    STEP(ii + 2, 6, 2, 1, 0, scA, d4A, gr0, gr1)
    STEP(ii + 3, 7, 3, 2, 1, scB, d4B, gr1, gr0)
    STEP(ii + 4, 0, 4, 3, 2, scA, d4A, gr0, gr1)
    STEP(ii + 5, 1, 5, 0, 3, scB, d4B, gr1, gr0)
    STEP(ii + 6, 2, 6, 1, 0, scA, d4A, gr0, gr1)
    STEP(ii + 7, 3, 7, 2, 1, scB, d4B, gr1, gr0)
  }
  // tail: i = 2044..2047
  STEP(2044, 4, 0, 3, 2, scA, d4A, gr0, gr1)
  STEP(2045, 5, 1, 0, 3, scB, d4B, gr1, gr0)
  STEP(2046, 6, 2, 1, 0, scA, d4A, gr0, gr1)
  STEP(2047, 7, 3, 2, 1, scB, d4B, gr1, gr0)
#undef STEP

  // final: h_2048 = rinv_2048 * s_2048 -> slot 2048
  const float rinvT = rsqrtf(fmaf(n, INVD, EPSV));
  float4 o;
  o.x = rinvT * s.x; o.y = rinvT * s.y; o.z = rinvT * s.z; o.w = rinvT * s.w;
  h4[(size_t)SLOT4C * T_STEPS + idx4] = o;
}

// ---------------- outs[t] = h_{t+1} * silu(h_{t+1}) ----------------
__global__ __launch_bounds__(256) void silu_kernel(const float4* __restrict__ hsrc,
                                                   float4* __restrict__ out4, int n4) {
  int i = blockIdx.x * blockDim.x + threadIdx.x;
  if (i >= n4) return;
  float4 h = hsrc[i];
  float4 o;
  o.x = h.x * h.x / (1.f + __expf(-h.x));
  o.y = h.y * h.y / (1.f + __expf(-h.y));
  o.z = h.z * h.z / (1.f + __expf(-h.z));
  o.w = h.w * h.w / (1.f + __expf(-h.w));
  out4[i] = o;
}

extern "C" void kernel_launch(void* const* d_in, const int* in_sizes, int n_in,
                              void* d_out, int out_size, void* d_ws, size_t ws_size,
                              hipStream_t stream) {
  (void)in_sizes; (void)n_in; (void)d_ws; (void)ws_size; (void)out_size;
  const float* x = (const float*)d_in[0];
  const float* h0 = (const float*)d_in[1];
  const float* W = (const float*)d_in[2];
  const float* bias = (const float*)d_in[3];
  const float* log_alpha = (const float*)d_in[4];

  float* out = (float*)d_out;                               // outs region [T][B][D]
  float* hreg = out + (size_t)T_STEPS * BATCH * DIM;        // h region [T+1][B][D]
  // staging overlays the outs region (consumed before scan/silu touch it)
  __hip_bfloat16* xb = (__hip_bfloat16*)d_out;
  __hip_bfloat16* wb = (__hip_bfloat16*)((char*)d_out + (size_t)T_STEPS * BATCH * DIM * 2);
  float4* scal4 = (float4*)(out + (size_t)26 * 1024 * 1024);  // 104 MB offset
  float* d4g = out + (size_t)27 * 1024 * 1024;                // 108 MB offset

  const int nx8 = T_STEPS * BATCH * DIM / 8;
  const int nw8 = DIM * DIM / 8;
  cvt_kernel<<<nx8 / 256, 256, 0, stream>>>(x, (bf16x8pack*)xb, nx8);
  cvt_kernel<<<nw8 / 256, 256, 0, stream>>>(W, (bf16x8pack*)wb, nw8);

  dim3 ggrid(DIM / 128, (T_STEPS * BATCH) / 128);
  gemm_kernel<<<ggrid, 256, 0, stream>>>(xb, wb, bias, log_alpha, hreg);

  dots_kernel<<<T_STEPS * BATCH, 64, 0, stream>>>(hreg, scal4, d4g);

  scan_kernel<<<BATCH, 256, 0, stream>>>(h0, scal4, d4g, hreg);

  const int n4 = T_STEPS * BATCH * DIM / 4;
  silu_kernel<<<n4 / 256, 256, 0, stream>>>((const float4*)(hreg + BATCH * DIM),
                                            (float4*)out, n4);
}

// Round 6
// 553.049 us; speedup vs baseline: 1.3459x; 1.0711x over previous
//
#include <hip/hip_runtime.h>
#include <hip/hip_bf16.h>

#define T_STEPS 2048
#define BATCH 16
#define DIM 1024
#define EPSV 1e-6f
#define INVD (1.0f / 1024.0f)
#define SLOTF (BATCH * DIM)      // floats per [B][D] slot
#define SLOT4C (BATCH * DIM / 4) // float4 per slot

typedef short short8 __attribute__((ext_vector_type(8)));
typedef float f32x4 __attribute__((ext_vector_type(4)));

struct alignas(16) bf16x8pack { __hip_bfloat16 v[8]; };

__device__ __forceinline__ float dot4(const float4& a, const float4& c) {
  return fmaf(a.x, c.x, fmaf(a.y, c.y, fmaf(a.z, c.z, a.w * c.w)));
}

// raw v_rsq_f32 (~16cy TRANS) instead of OCML precise rsqrt (serial chain!)
__device__ __forceinline__ float fast_rsq(float x) {
  float r;
  asm("v_rsq_f32 %0, %1" : "=v"(r) : "v"(x));
  return r;
}

// ---------------- fp32 -> bf16 convert (vectorized) ----------------
__global__ __launch_bounds__(256) void cvt_kernel(const float* __restrict__ src,
                                                  bf16x8pack* __restrict__ dst, int n8) {
  int i = blockIdx.x * blockDim.x + threadIdx.x;
  if (i >= n8) return;
  const float4* s4 = (const float4*)src + (size_t)i * 2;
  float4 a = s4[0];
  float4 b = s4[1];
  bf16x8pack p;
  p.v[0] = __float2bfloat16(a.x); p.v[1] = __float2bfloat16(a.y);
  p.v[2] = __float2bfloat16(a.z); p.v[3] = __float2bfloat16(a.w);
  p.v[4] = __float2bfloat16(b.x); p.v[5] = __float2bfloat16(b.y);
  p.v[6] = __float2bfloat16(b.z); p.v[7] = __float2bfloat16(b.w);
  dst[i] = p;
}

// ---------------- bf16 MFMA GEMM: out[m][e] = alpha*(sum_d X[m][d]*W[e][d] + b[e]) ----
__global__ __launch_bounds__(256) void gemm_kernel(
    const __hip_bfloat16* __restrict__ Xb,
    const __hip_bfloat16* __restrict__ Wb,
    const float* __restrict__ bias,
    const float* __restrict__ log_alpha_p,
    float* __restrict__ hreg) {
  __shared__ __hip_bfloat16 As[128 * 32];
  __shared__ __hip_bfloat16 Bs[128 * 32];
  const int tid = threadIdx.x;
  const int wave = tid >> 6, lane = tid & 63;
  const int m0 = blockIdx.y * 128;
  const int e0 = blockIdx.x * 128;
  const int wm = (wave >> 1) * 64;
  const int wn = (wave & 1) * 64;
  const int l15 = lane & 15, l4 = lane >> 4;

  f32x4 acc[4][4] = {};

  const int srow = wave * 16 + (lane >> 2);
  const int sch = (lane & 3) * 8;

  for (int kt = 0; kt < DIM; kt += 32) {
    __syncthreads();
#pragma unroll
    for (int i = 0; i < 2; ++i) {
      const __hip_bfloat16* ga = Xb + (size_t)(m0 + i * 64 + srow) * DIM + kt + sch;
      const __hip_bfloat16* gb = Wb + (size_t)(e0 + i * 64 + srow) * DIM + kt + sch;
      __builtin_amdgcn_global_load_lds(
          (const __attribute__((address_space(1))) void*)ga,
          (__attribute__((address_space(3))) void*)((char*)As + (i * 64 + wave * 16) * 64),
          16, 0, 0);
      __builtin_amdgcn_global_load_lds(
          (const __attribute__((address_space(1))) void*)gb,
          (__attribute__((address_space(3))) void*)((char*)Bs + (i * 64 + wave * 16) * 64),
          16, 0, 0);
    }
    __syncthreads();
    short8 a[4], b[4];
#pragma unroll
    for (int f = 0; f < 4; ++f)
      a[f] = *(const short8*)((const char*)As + ((wm + f * 16 + l15) * 32 + l4 * 8) * 2);
#pragma unroll
    for (int g = 0; g < 4; ++g)
      b[g] = *(const short8*)((const char*)Bs + ((wn + g * 16 + l15) * 32 + l4 * 8) * 2);
#pragma unroll
    for (int f = 0; f < 4; ++f)
#pragma unroll
      for (int g = 0; g < 4; ++g)
        acc[f][g] = __builtin_amdgcn_mfma_f32_16x16x32_bf16(a[f], b[g], acc[f][g], 0, 0, 0);
  }
  const float alpha = __expf(log_alpha_p[0]);
#pragma unroll
  for (int g = 0; g < 4; ++g) {
    const int e = e0 + wn + g * 16 + l15;
    const float bv = bias[e];
#pragma unroll
    for (int f = 0; f < 4; ++f) {
#pragma unroll
      for (int r = 0; r < 4; ++r) {
        const int m = m0 + wm + f * 16 + l4 * 4 + r;
        hreg[(size_t)(m + BATCH) * DIM + e] = alpha * (acc[f][g][r] + bv);
      }
    }
  }
}

// ---------------- DPP wave-sum helper (total lands in lane 63) ----------------
__device__ __forceinline__ float dpp_sum_reg(float x) {
  float acc = x;
#define DPP_ADD(ctrl)                                                              \
  {                                                                                \
    int t_ = __builtin_amdgcn_update_dpp(0, __float_as_int(acc), (ctrl), 0xf, 0xf, \
                                         true);                                    \
    acc += __int_as_float(t_);                                                     \
  }
  DPP_ADD(0x111); DPP_ADD(0x112); DPP_ADD(0x114); DPP_ADD(0x118);
  DPP_ADD(0x142); DPP_ADD(0x143);
#undef DPP_ADD
  return acc;
}

// ---- precompute: scal4[t]=(e, 2d, 2d2, 2d3), d45[t]=(2d4, 2d5)  (dk = W_{t-k}.W_t) ----
__global__ __launch_bounds__(64) void dots_kernel(const float* __restrict__ hreg,
                                                  float4* __restrict__ scal4,
                                                  float2* __restrict__ d45g) {
  const int t = blockIdx.x >> 4;
  const int b = blockIdx.x & 15;
  const int lane = threadIdx.x;
  const float4* w  = (const float4*)(hreg + (size_t)(t + 1) * SLOTF + b * DIM);
  const float4* m1 = (const float4*)(hreg + (size_t)(t    ) * SLOTF + b * DIM);
  const float4* m2 = (const float4*)(hreg + (size_t)(t - 1) * SLOTF + b * DIM);
  const float4* m3 = (const float4*)(hreg + (size_t)(t - 2) * SLOTF + b * DIM);
  const float4* m4 = (const float4*)(hreg + (size_t)(t - 3) * SLOTF + b * DIM);
  const float4* m5 = (const float4*)(hreg + (size_t)(t - 4) * SLOTF + b * DIM);
  float e = 0.f, d = 0.f, d2 = 0.f, d3 = 0.f, d4 = 0.f, d5 = 0.f;
#pragma unroll
  for (int j = 0; j < 4; ++j) {
    float4 a = w[lane + 64 * j];
    e = fmaf(a.x, a.x, fmaf(a.y, a.y, fmaf(a.z, a.z, fmaf(a.w, a.w, e))));
    if (t >= 1) { float4 p = m1[lane + 64 * j];
      d = fmaf(p.x, a.x, fmaf(p.y, a.y, fmaf(p.z, a.z, fmaf(p.w, a.w, d)))); }
    if (t >= 2) { float4 p = m2[lane + 64 * j];
      d2 = fmaf(p.x, a.x, fmaf(p.y, a.y, fmaf(p.z, a.z, fmaf(p.w, a.w, d2)))); }
    if (t >= 3) { float4 p = m3[lane + 64 * j];
      d3 = fmaf(p.x, a.x, fmaf(p.y, a.y, fmaf(p.z, a.z, fmaf(p.w, a.w, d3)))); }
    if (t >= 4) { float4 p = m4[lane + 64 * j];
      d4 = fmaf(p.x, a.x, fmaf(p.y, a.y, fmaf(p.z, a.z, fmaf(p.w, a.w, d4)))); }
    if (t >= 5) { float4 p = m5[lane + 64 * j];
      d5 = fmaf(p.x, a.x, fmaf(p.y, a.y, fmaf(p.z, a.z, fmaf(p.w, a.w, d5)))); }
  }
  e = dpp_sum_reg(e);
  d = dpp_sum_reg(d);
  d2 = dpp_sum_reg(d2);
  d3 = dpp_sum_reg(d3);
  d4 = dpp_sum_reg(d4);
  d5 = dpp_sum_reg(d5);
  if (lane == 63) {
    scal4[b * T_STEPS + t] = make_float4(e, d + d, d2 + d2, d3 + d3);
    d45g[b * T_STEPS + t] = make_float2(d4 + d4, d5 + d5);
  }
}

// ---------------- sequential scan, 4 waves/row, depth-5 pipeline, barrier/2 steps ----
// s_{i+1}=h_i+W_i, h_i=rinv_i*s_i, n_{i+1}=rinv^2 n + 2 rinv b_i + e_i,
// 2b_i = 2d + r1(2d2 + r2(2d3 + r3(2d4 + r4(2d5 + 2G)))), G_i = h_{i-5}.W_i.
// G pipeline: partial@p (targets p+5) -> write@p+1 (slot (p+5)&3) -> read@p+3
// -> combine@p+4 -> use@p+5.  Barrier + lgkmcnt(0) only after ODD steps: any
// write@j / read@j+2 pair straddles >=1 barrier.  Ring-16 W prefetch (11-step
// cover); global queue never drained (no vmcnt waits).
__global__ __launch_bounds__(256, 1) void scan_kernel(
    const float* __restrict__ h0,
    const float4* __restrict__ scal4,
    const float2* __restrict__ d45g,
    float* __restrict__ hreg) {
  const int b = blockIdx.x;
  const int tid = threadIdx.x;
  const int wave = tid >> 6;
  const int lane = tid & 63;
  float4* h4 = (float4*)hreg;
  const int idx4 = b * 256 + tid;

  __shared__ float4 scLDS[T_STEPS];          // 32 KB
  __shared__ float2 d45LDS[T_STEPS];         // 16 KB
  __shared__ alignas(16) float Gp[4][4];     // [target&3][wave]
  __shared__ float initP[4][6];

#pragma unroll
  for (int p = 0; p < 8; ++p)
    scLDS[p * 256 + tid] = scal4[b * T_STEPS + p * 256 + tid];
#pragma unroll
  for (int p = 0; p < 8; ++p)
    d45LDS[p * 256 + tid] = d45g[b * T_STEPS + p * 256 + tid];

  // W ring-16: w[k] = W_k for k=2..15, w[0]=W_16, w[1]=W_17  (W_j at hreg slot j+1)
  float4 w[16];
#pragma unroll
  for (int k = 2; k < 16; ++k) w[k] = h4[(size_t)SLOT4C * (k + 1) + idx4];
  w[0] = h4[(size_t)SLOT4C * 17 + idx4];
  w[1] = h4[(size_t)SLOT4C * 18 + idx4];
  float4 w0v = h4[(size_t)SLOT4C * 1 + idx4];  // W_0
  float4 w1v = h4[(size_t)SLOT4C * 2 + idx4];  // W_1
  float4 h0v = ((const float4*)h0)[idx4];
  h4[idx4] = h0v;  // slot 0 = h_0

  // startup direct reductions off s_1 = h_0 + W_0
  float4 s;
  s.x = h0v.x + w0v.x; s.y = h0v.y + w0v.y;
  s.z = h0v.z + w0v.z; s.w = h0v.w + w0v.w;
  {
    float q  = dpp_sum_reg(dot4(s, s));
    float r  = dpp_sum_reg(dot4(s, w1v));
    float c2 = dpp_sum_reg(dot4(s, w[2]));
    float c3 = dpp_sum_reg(dot4(s, w[3]));
    float c4 = dpp_sum_reg(dot4(s, w[4]));
    float c5 = dpp_sum_reg(dot4(s, w[5]));
    if (lane == 63) {
      initP[wave][0] = q;  initP[wave][1] = r;  initP[wave][2] = c2;
      initP[wave][3] = c3; initP[wave][4] = c4; initP[wave][5] = c5;
    }
  }
  __syncthreads();
  const float n1 = (initP[0][0] + initP[1][0]) + (initP[2][0] + initP[3][0]);
  float t1 = (initP[0][1] + initP[1][1]) + (initP[2][1] + initP[3][1]);
  float t2 = (initP[0][2] + initP[1][2]) + (initP[2][2] + initP[3][2]);
  float t3 = (initP[0][3] + initP[1][3]) + (initP[2][3] + initP[3][3]);
  float t4 = (initP[0][4] + initP[1][4]) + (initP[2][4] + initP[3][4]);
  float t5 = (initP[0][5] + initP[1][5]) + (initP[2][5] + initP[3][5]);
  const float B1 = t1 + t1, C2 = t2 + t2, C3 = t3 + t3, C4 = t4 + t4, C5 = t5 + t5;

  const float e1 = scLDS[1].x;
  float4 sc2 = scLDS[2], sc3 = scLDS[3], sc4 = scLDS[4], sc5 = scLDS[5];
  const float D45x = d45LDS[5].x;  // 2*d4_5
  float4 scA = scLDS[6], scB = scLDS[7];
  float2 d45A = d45LDS[6], d45B = d45LDS[7];

  float n = n1, rm1, rm2, rm3, rm4, pp;
  float gr0 = 0.f, gr1 = 0.f;
  float4 rv = make_float4(0.f, 0.f, 0.f, 0.f);

#define BAR1 { asm volatile("s_waitcnt lgkmcnt(0)" ::: "memory"); __builtin_amdgcn_s_barrier(); }

  // ---- step 1
  {
    const float rinv = fast_rsq(fmaf(n, INVD, EPSV));
    n = fmaf(rinv, fmaf(rinv, n, B1), e1);
    float4 hv;
    hv.x = rinv * s.x; hv.y = rinv * s.y; hv.z = rinv * s.z; hv.w = rinv * s.w;
    h4[(size_t)SLOT4C * 1 + idx4] = hv;
    s.x = hv.x + w1v.x; s.y = hv.y + w1v.y; s.z = hv.z + w1v.z; s.w = hv.w + w1v.w;
    pp = dpp_sum_reg(dot4(hv, w[6]));  // G_6 partial
    rm1 = rinv;
    BAR1
  }
  // ---- step 2
  {
    if (lane == 63) Gp[2][wave] = pp;  // target 6
    const float rinv = fast_rsq(fmaf(n, INVD, EPSV));
    const float BB = fmaf(rm1, C2, sc2.y);
    n = fmaf(rinv, fmaf(rinv, n, BB), sc2.x);
    float4 hv;
    hv.x = rinv * s.x; hv.y = rinv * s.y; hv.z = rinv * s.z; hv.w = rinv * s.w;
    h4[(size_t)SLOT4C * 2 + idx4] = hv;
    s.x = hv.x + w[2].x; s.y = hv.y + w[2].y; s.z = hv.z + w[2].z; s.w = hv.w + w[2].w;
    pp = dpp_sum_reg(dot4(hv, w[7]));  // G_7 partial
    w[2] = h4[(size_t)SLOT4C * 19 + idx4];  // W_18
    rm2 = rm1; rm1 = rinv;
    BAR1
  }
  // ---- step 3
  {
    if (lane == 63) Gp[3][wave] = pp;  // target 7
    const float rinv = fast_rsq(fmaf(n, INVD, EPSV));
    const float BB = fmaf(rm1, fmaf(rm2, C3, sc3.z), sc3.y);
    n = fmaf(rinv, fmaf(rinv, n, BB), sc3.x);
    float4 hv;
    hv.x = rinv * s.x; hv.y = rinv * s.y; hv.z = rinv * s.z; hv.w = rinv * s.w;
    h4[(size_t)SLOT4C * 3 + idx4] = hv;
    s.x = hv.x + w[3].x; s.y = hv.y + w[3].y; s.z = hv.z + w[3].z; s.w = hv.w + w[3].w;
    pp = dpp_sum_reg(dot4(hv, w[8]));  // G_8 partial
    w[3] = h4[(size_t)SLOT4C * 20 + idx4];  // W_19
    rm3 = rm2; rm2 = rm1; rm1 = rinv;
    BAR1
  }
  // ---- step 4
  {
    if (lane == 63) Gp[0][wave] = pp;  // target 8
    const float rinv = fast_rsq(fmaf(n, INVD, EPSV));
    const float BB = fmaf(rm1, fmaf(rm2, fmaf(rm3, C4, sc4.w), sc4.z), sc4.y);
    n = fmaf(rinv, fmaf(rinv, n, BB), sc4.x);
    rv = *(const float4*)&Gp[2][0];  // target-6 partials
    float4 hv;
    hv.x = rinv * s.x; hv.y = rinv * s.y; hv.z = rinv * s.z; hv.w = rinv * s.w;
    h4[(size_t)SLOT4C * 4 + idx4] = hv;
    s.x = hv.x + w[4].x; s.y = hv.y + w[4].y; s.z = hv.z + w[4].z; s.w = hv.w + w[4].w;
    pp = dpp_sum_reg(dot4(hv, w[9]));  // G_9 partial
    w[4] = h4[(size_t)SLOT4C * 21 + idx4];  // W_20
    rm4 = rm3; rm3 = rm2; rm2 = rm1; rm1 = rinv;
    BAR1
  }
  // ---- step 5
  {
    if (lane == 63) Gp[1][wave] = pp;  // target 9
    const float rinv = fast_rsq(fmaf(n, INVD, EPSV));
    const float BB =
        fmaf(rm1, fmaf(rm2, fmaf(rm3, fmaf(rm4, C5, D45x), sc5.w), sc5.z), sc5.y);
    n = fmaf(rinv, fmaf(rinv, n, BB), sc5.x);
    { float gt = (rv.x + rv.y) + (rv.z + rv.w); gr0 = gt + gt; }  // 2*G_6
    rv = *(const float4*)&Gp[3][0];  // target-7 partials
    float4 hv;
    hv.x = rinv * s.x; hv.y = rinv * s.y; hv.z = rinv * s.z; hv.w = rinv * s.w;
    h4[(size_t)SLOT4C * 5 + idx4] = hv;
    s.x = hv.x + w[5].x; s.y = hv.y + w[5].y; s.z = hv.z + w[5].z; s.w = hv.w + w[5].w;
    pp = dpp_sum_reg(dot4(hv, w[10]));  // G_10 partial
    w[5] = h4[(size_t)SLOT4C * 22 + idx4];  // W_21
    rm4 = rm3; rm3 = rm2; rm2 = rm1; rm1 = rinv;
    BAR1
  }

// Steady step i>=6. Order: write pp(target i+4) | BB uses gr[i&1] | combine
// rv->gr[(i+1)&1] | read rv=Gp[(i+2)&3] | body | prefetch | sc/d45 read-ahead.
#define STEP(I_, WS, W5S, GW, GR, SCR, D45R, GRU, GRW, BAR_)                         \
  {                                                                                  \
    const int i_ = (I_);                                                             \
    if (lane == 63) Gp[GW][wave] = pp;                                               \
    const float rinv = fast_rsq(fmaf(n, INVD, EPSV));                                \
    const float BB = fmaf(                                                           \
        rm1, fmaf(rm2, fmaf(rm3, fmaf(rm4, (D45R).y + (GRU), (D45R).x), (SCR).w),    \
                  (SCR).z), (SCR).y);                                                \
    n = fmaf(rinv, fmaf(rinv, n, BB), (SCR).x);                                      \
    { float gt_ = (rv.x + rv.y) + (rv.z + rv.w); GRW = gt_ + gt_; }                  \
    rv = *(const float4*)&Gp[GR][0];                                                 \
    float4 hv_;                                                                      \
    hv_.x = rinv * s.x; hv_.y = rinv * s.y;                                          \
    hv_.z = rinv * s.z; hv_.w = rinv * s.w;                                          \
    h4[(size_t)SLOT4C * i_ + idx4] = hv_;                                            \
    s.x = hv_.x + w[WS].x; s.y = hv_.y + w[WS].y;                                    \
    s.z = hv_.z + w[WS].z; s.w = hv_.w + w[WS].w;                                    \
    pp = dpp_sum_reg(dot4(hv_, w[W5S]));                                             \
    const int ipf_ = (i_ + 16 < T_STEPS) ? (i_ + 16) : (T_STEPS - 1);                \
    w[WS] = h4[(size_t)SLOT4C * (ipf_ + 1) + idx4];                                  \
    const int isc_ = (i_ + 2 < T_STEPS) ? (i_ + 2) : (T_STEPS - 1);                  \
    SCR = scLDS[isc_];                                                               \
    D45R = d45LDS[isc_];                                                             \
    rm4 = rm3; rm3 = rm2; rm2 = rm1; rm1 = rinv;                                     \
    if (BAR_) BAR1                                                                   \
  }

  // main loop: i = 6..2037 in chunks of 16 (ii ≡ 6 mod 16)
  for (int ii = 6; ii < 2038; ii += 16) {
    STEP(ii + 0,  6, 11, 2, 0, scA, d45A, gr0, gr1, 0)
    STEP(ii + 1,  7, 12, 3, 1, scB, d45B, gr1, gr0, 1)
    STEP(ii + 2,  8, 13, 0, 2, scA, d45A, gr0, gr1, 0)
    STEP(ii + 3,  9, 14, 1, 3, scB, d45B, gr1, gr0, 1)
    STEP(ii + 4, 10, 15, 2, 0, scA, d45A, gr0, gr1, 0)
    STEP(ii + 5, 11,  0, 3, 1, scB, d45B, gr1, gr0, 1)
    STEP(ii + 6, 12,  1, 0, 2, scA, d45A, gr0, gr1, 0)
    STEP(ii + 7, 13,  2, 1, 3, scB, d45B, gr1, gr0, 1)
    STEP(ii + 8, 14,  3, 2, 0, scA, d45A, gr0, gr1, 0)
    STEP(ii + 9, 15,  4, 3, 1, scB, d45B, gr1, gr0, 1)
    STEP(ii + 10, 0,  5, 0, 2, scA, d45A, gr0, gr1, 0)
    STEP(ii + 11, 1,  6, 1, 3, scB, d45B, gr1, gr0, 1)
    STEP(ii + 12, 2,  7, 2, 0, scA, d45A, gr0, gr1, 0)
    STEP(ii + 13, 3,  8, 3, 1, scB, d45B, gr1, gr0, 1)
    STEP(ii + 14, 4,  9, 0, 2, scA, d45A, gr0, gr1, 0)
    STEP(ii + 15, 5, 10, 1, 3, scB, d45B, gr1, gr0, 1)
  }
  // tail: i = 2038..2047 (continues k-pattern, 2038 ≡ 6 mod 16)
  STEP(2038,  6, 11, 2, 0, scA, d45A, gr0, gr1, 0)
  STEP(2039,  7, 12, 3, 1, scB, d45B, gr1, gr0, 1)
  STEP(2040,  8, 13, 0, 2, scA, d45A, gr0, gr1, 0)
  STEP(2041,  9, 14, 1, 3, scB, d45B, gr1, gr0, 1)
  STEP(2042, 10, 15, 2, 0, scA, d45A, gr0, gr1, 0)
  STEP(2043, 11,  0, 3, 1, scB, d45B, gr1, gr0, 1)
  STEP(2044, 12,  1, 0, 2, scA, d45A, gr0, gr1, 0)
  STEP(2045, 13,  2, 1, 3, scB, d45B, gr1, gr0, 1)
  STEP(2046, 14,  3, 2, 0, scA, d45A, gr0, gr1, 0)
  STEP(2047, 15,  4, 3, 1, scB, d45B, gr1, gr0, 1)
#undef STEP
#undef BAR1

  // final: h_2048 = rinv * s -> slot 2048
  const float rinvT = fast_rsq(fmaf(n, INVD, EPSV));
  float4 o;
  o.x = rinvT * s.x; o.y = rinvT * s.y; o.z = rinvT * s.z; o.w = rinvT * s.w;
  h4[(size_t)SLOT4C * T_STEPS + idx4] = o;
}

// ---------------- outs[t] = h_{t+1} * silu(h_{t+1}) ----------------
__global__ __launch_bounds__(256) void silu_kernel(const float4* __restrict__ hsrc,
                                                   float4* __restrict__ out4, int n4) {
  int i = blockIdx.x * blockDim.x + threadIdx.x;
  if (i >= n4) return;
  float4 h = hsrc[i];
  float4 o;
  o.x = h.x * h.x / (1.f + __expf(-h.x));
  o.y = h.y * h.y / (1.f + __expf(-h.y));
  o.z = h.z * h.z / (1.f + __expf(-h.z));
  o.w = h.w * h.w / (1.f + __expf(-h.w));
  out4[i] = o;
}

extern "C" void kernel_launch(void* const* d_in, const int* in_sizes, int n_in,
                              void* d_out, int out_size, void* d_ws, size_t ws_size,
                              hipStream_t stream) {
  (void)in_sizes; (void)n_in; (void)d_ws; (void)ws_size; (void)out_size;
  const float* x = (const float*)d_in[0];
  const float* h0 = (const float*)d_in[1];
  const float* W = (const float*)d_in[2];
  const float* bias = (const float*)d_in[3];
  const float* log_alpha = (const float*)d_in[4];

  float* out = (float*)d_out;                               // outs region [T][B][D]
  float* hreg = out + (size_t)T_STEPS * BATCH * DIM;        // h region [T+1][B][D]
  // staging overlays the outs region (consumed before scan/silu touch it)
  __hip_bfloat16* xb = (__hip_bfloat16*)d_out;
  __hip_bfloat16* wb = (__hip_bfloat16*)((char*)d_out + (size_t)T_STEPS * BATCH * DIM * 2);
  float4* scal4 = (float4*)(out + (size_t)26 * 1024 * 1024);  // 104 MB offset
  float2* d45g = (float2*)(out + (size_t)27 * 1024 * 1024);   // 108 MB offset

  const int nx8 = T_STEPS * BATCH * DIM / 8;
  const int nw8 = DIM * DIM / 8;
  cvt_kernel<<<nx8 / 256, 256, 0, stream>>>(x, (bf16x8pack*)xb, nx8);
  cvt_kernel<<<nw8 / 256, 256, 0, stream>>>(W, (bf16x8pack*)wb, nw8);

  dim3 ggrid(DIM / 128, (T_STEPS * BATCH) / 128);
  gemm_kernel<<<ggrid, 256, 0, stream>>>(xb, wb, bias, log_alpha, hreg);

  dots_kernel<<<T_STEPS * BATCH, 64, 0, stream>>>(hreg, scal4, d45g);

  scan_kernel<<<BATCH, 256, 0, stream>>>(h0, scal4, d45g, hreg);

  const int n4 = T_STEPS * BATCH * DIM / 4;
  silu_kernel<<<n4 / 256, 256, 0, stream>>>((const float4*)(hreg + BATCH * DIM),
                                            (float4*)out, n4);
}

// Round 7
// 538.365 us; speedup vs baseline: 1.3826x; 1.0273x over previous
//
#include <hip/hip_runtime.h>
#include <hip/hip_bf16.h>

#define T_STEPS 2048
#define BATCH 16
#define DIM 1024
#define EPSV 1e-6f
#define INVD (1.0f / 1024.0f)
#define SLOTF (BATCH * DIM)      // floats per [B][D] slot
#define SLOT4C (BATCH * DIM / 4) // float4 per slot

typedef short short8 __attribute__((ext_vector_type(8)));
typedef float f32x4 __attribute__((ext_vector_type(4)));

struct alignas(16) bf16x8pack { __hip_bfloat16 v[8]; };

__device__ __forceinline__ float dot4(const float4& a, const float4& c) {
  return fmaf(a.x, c.x, fmaf(a.y, c.y, fmaf(a.z, c.z, a.w * c.w)));
}

// raw v_rsq_f32 (~16cy TRANS) instead of OCML precise rsqrt (serial chain!)
__device__ __forceinline__ float fast_rsq(float x) {
  float r;
  asm("v_rsq_f32 %0, %1" : "=v"(r) : "v"(x));
  return r;
}

// ---------------- fp32 -> bf16 convert (vectorized) ----------------
__global__ __launch_bounds__(256) void cvt_kernel(const float* __restrict__ src,
                                                  bf16x8pack* __restrict__ dst, int n8) {
  int i = blockIdx.x * blockDim.x + threadIdx.x;
  if (i >= n8) return;
  const float4* s4 = (const float4*)src + (size_t)i * 2;
  float4 a = s4[0];
  float4 b = s4[1];
  bf16x8pack p;
  p.v[0] = __float2bfloat16(a.x); p.v[1] = __float2bfloat16(a.y);
  p.v[2] = __float2bfloat16(a.z); p.v[3] = __float2bfloat16(a.w);
  p.v[4] = __float2bfloat16(b.x); p.v[5] = __float2bfloat16(b.y);
  p.v[6] = __float2bfloat16(b.z); p.v[7] = __float2bfloat16(b.w);
  dst[i] = p;
}

// ---------------- bf16 MFMA GEMM: out[m][e] = alpha*(sum_d X[m][d]*W[e][d] + b[e]) ----
__global__ __launch_bounds__(256) void gemm_kernel(
    const __hip_bfloat16* __restrict__ Xb,
    const __hip_bfloat16* __restrict__ Wb,
    const float* __restrict__ bias,
    const float* __restrict__ log_alpha_p,
    float* __restrict__ hreg) {
  __shared__ __hip_bfloat16 As[128 * 32];
  __shared__ __hip_bfloat16 Bs[128 * 32];
  const int tid = threadIdx.x;
  const int wave = tid >> 6, lane = tid & 63;
  const int m0 = blockIdx.y * 128;
  const int e0 = blockIdx.x * 128;
  const int wm = (wave >> 1) * 64;
  const int wn = (wave & 1) * 64;
  const int l15 = lane & 15, l4 = lane >> 4;

  f32x4 acc[4][4] = {};

  const int srow = wave * 16 + (lane >> 2);
  const int sch = (lane & 3) * 8;

  for (int kt = 0; kt < DIM; kt += 32) {
    __syncthreads();
#pragma unroll
    for (int i = 0; i < 2; ++i) {
      const __hip_bfloat16* ga = Xb + (size_t)(m0 + i * 64 + srow) * DIM + kt + sch;
      const __hip_bfloat16* gb = Wb + (size_t)(e0 + i * 64 + srow) * DIM + kt + sch;
      __builtin_amdgcn_global_load_lds(
          (const __attribute__((address_space(1))) void*)ga,
          (__attribute__((address_space(3))) void*)((char*)As + (i * 64 + wave * 16) * 64),
          16, 0, 0);
      __builtin_amdgcn_global_load_lds(
          (const __attribute__((address_space(1))) void*)gb,
          (__attribute__((address_space(3))) void*)((char*)Bs + (i * 64 + wave * 16) * 64),
          16, 0, 0);
    }
    __syncthreads();
    short8 a[4], b[4];
#pragma unroll
    for (int f = 0; f < 4; ++f)
      a[f] = *(const short8*)((const char*)As + ((wm + f * 16 + l15) * 32 + l4 * 8) * 2);
#pragma unroll
    for (int g = 0; g < 4; ++g)
      b[g] = *(const short8*)((const char*)Bs + ((wn + g * 16 + l15) * 32 + l4 * 8) * 2);
#pragma unroll
    for (int f = 0; f < 4; ++f)
#pragma unroll
      for (int g = 0; g < 4; ++g)
        acc[f][g] = __builtin_amdgcn_mfma_f32_16x16x32_bf16(a[f], b[g], acc[f][g], 0, 0, 0);
  }
  const float alpha = __expf(log_alpha_p[0]);
#pragma unroll
  for (int g = 0; g < 4; ++g) {
    const int e = e0 + wn + g * 16 + l15;
    const float bv = bias[e];
#pragma unroll
    for (int f = 0; f < 4; ++f) {
#pragma unroll
      for (int r = 0; r < 4; ++r) {
        const int m = m0 + wm + f * 16 + l4 * 4 + r;
        hreg[(size_t)(m + BATCH) * DIM + e] = alpha * (acc[f][g][r] + bv);
      }
    }
  }
}

// ---------------- DPP wave-sum helper (total lands in lane 63) ----------------
__device__ __forceinline__ float dpp_sum_reg(float x) {
  float acc = x;
#define DPP_ADD(ctrl)                                                              \
  {                                                                                \
    int t_ = __builtin_amdgcn_update_dpp(0, __float_as_int(acc), (ctrl), 0xf, 0xf, \
                                         true);                                    \
    acc += __int_as_float(t_);                                                     \
  }
  DPP_ADD(0x111); DPP_ADD(0x112); DPP_ADD(0x114); DPP_ADD(0x118);
  DPP_ADD(0x142); DPP_ADD(0x143);
#undef DPP_ADD
  return acc;
}

// ---- precompute: scal4[t]=(e, 2d, 2d2, 2d3), d45[t]=(2d4, 2d5)  (dk = W_{t-k}.W_t) ----
__global__ __launch_bounds__(64) void dots_kernel(const float* __restrict__ hreg,
                                                  float4* __restrict__ scal4,
                                                  float2* __restrict__ d45g) {
  const int t = blockIdx.x >> 4;
  const int b = blockIdx.x & 15;
  const int lane = threadIdx.x;
  const float4* w  = (const float4*)(hreg + (size_t)(t + 1) * SLOTF + b * DIM);
  const float4* m1 = (const float4*)(hreg + (size_t)(t    ) * SLOTF + b * DIM);
  const float4* m2 = (const float4*)(hreg + (size_t)(t - 1) * SLOTF + b * DIM);
  const float4* m3 = (const float4*)(hreg + (size_t)(t - 2) * SLOTF + b * DIM);
  const float4* m4 = (const float4*)(hreg + (size_t)(t - 3) * SLOTF + b * DIM);
  const float4* m5 = (const float4*)(hreg + (size_t)(t - 4) * SLOTF + b * DIM);
  float e = 0.f, d = 0.f, d2 = 0.f, d3 = 0.f, d4 = 0.f, d5 = 0.f;
#pragma unroll
  for (int j = 0; j < 4; ++j) {
    float4 a = w[lane + 64 * j];
    e = fmaf(a.x, a.x, fmaf(a.y, a.y, fmaf(a.z, a.z, fmaf(a.w, a.w, e))));
    if (t >= 1) { float4 p = m1[lane + 64 * j];
      d = fmaf(p.x, a.x, fmaf(p.y, a.y, fmaf(p.z, a.z, fmaf(p.w, a.w, d)))); }
    if (t >= 2) { float4 p = m2[lane + 64 * j];
      d2 = fmaf(p.x, a.x, fmaf(p.y, a.y, fmaf(p.z, a.z, fmaf(p.w, a.w, d2)))); }
    if (t >= 3) { float4 p = m3[lane + 64 * j];
      d3 = fmaf(p.x, a.x, fmaf(p.y, a.y, fmaf(p.z, a.z, fmaf(p.w, a.w, d3)))); }
    if (t >= 4) { float4 p = m4[lane + 64 * j];
      d4 = fmaf(p.x, a.x, fmaf(p.y, a.y, fmaf(p.z, a.z, fmaf(p.w, a.w, d4)))); }
    if (t >= 5) { float4 p = m5[lane + 64 * j];
      d5 = fmaf(p.x, a.x, fmaf(p.y, a.y, fmaf(p.z, a.z, fmaf(p.w, a.w, d5)))); }
  }
  e = dpp_sum_reg(e);
  d = dpp_sum_reg(d);
  d2 = dpp_sum_reg(d2);
  d3 = dpp_sum_reg(d3);
  d4 = dpp_sum_reg(d4);
  d5 = dpp_sum_reg(d5);
  if (lane == 63) {
    scal4[b * T_STEPS + t] = make_float4(e, d + d, d2 + d2, d3 + d3);
    d45g[b * T_STEPS + t] = make_float2(d4 + d4, d5 + d5);
  }
}

// ---------------- sequential scan, 4 waves/row, depth-5 pipeline ----------------
// s_{i+1}=h_i+W_i, h_i=rinv_i*s_i, n_{i+1}=rinv^2 n + 2 rinv b_i + e_i,
// 2b_i = 2d + r1(2d2 + r2(2d3 + r3(2d4 + r4(2d5 + 2G)))), G_i = h_{i-5}.W_i.
// KEY (r7): 4-deep hv STORE RING so the implicit vmcnt wait before redefining
// the store-data regs references the store 4 steps back (~600cy slack), not the
// previous step's (store-ack ~300cy was the hidden floor).  Barrier every 2
// steps with counted lgkmcnt(3) (DS in-order; confirms only the Gp write).
__global__ __launch_bounds__(256, 1) void scan_kernel(
    const float* __restrict__ h0,
    const float4* __restrict__ scal4,
    const float2* __restrict__ d45g,
    float* __restrict__ hreg) {
  const int b = blockIdx.x;
  const int tid = threadIdx.x;
  const int wave = tid >> 6;
  const int lane = tid & 63;
  float4* h4 = (float4*)hreg;
  const int idx4 = b * 256 + tid;

  __shared__ float4 scLDS[T_STEPS];          // 32 KB
  __shared__ float2 d45LDS[T_STEPS];         // 16 KB
  __shared__ alignas(16) float Gp[4][4];     // [target&3][wave]
  __shared__ float initP[4][6];

#pragma unroll
  for (int p = 0; p < 8; ++p)
    scLDS[p * 256 + tid] = scal4[b * T_STEPS + p * 256 + tid];
#pragma unroll
  for (int p = 0; p < 8; ++p)
    d45LDS[p * 256 + tid] = d45g[b * T_STEPS + p * 256 + tid];

  // W ring-16: w[k] = W_k for k=2..15, w[0]=W_16, w[1]=W_17  (W_j at hreg slot j+1)
  float4 w[16];
#pragma unroll
  for (int k = 2; k < 16; ++k) w[k] = h4[(size_t)SLOT4C * (k + 1) + idx4];
  w[0] = h4[(size_t)SLOT4C * 17 + idx4];
  w[1] = h4[(size_t)SLOT4C * 18 + idx4];
  float4 w0v = h4[(size_t)SLOT4C * 1 + idx4];  // W_0
  float4 w1v = h4[(size_t)SLOT4C * 2 + idx4];  // W_1
  float4 h0v = ((const float4*)h0)[idx4];
  h4[idx4] = h0v;  // slot 0 = h_0

  // startup direct reductions off s_1 = h_0 + W_0
  float4 s;
  s.x = h0v.x + w0v.x; s.y = h0v.y + w0v.y;
  s.z = h0v.z + w0v.z; s.w = h0v.w + w0v.w;
  {
    float q  = dpp_sum_reg(dot4(s, s));
    float r  = dpp_sum_reg(dot4(s, w1v));
    float c2 = dpp_sum_reg(dot4(s, w[2]));
    float c3 = dpp_sum_reg(dot4(s, w[3]));
    float c4 = dpp_sum_reg(dot4(s, w[4]));
    float c5 = dpp_sum_reg(dot4(s, w[5]));
    if (lane == 63) {
      initP[wave][0] = q;  initP[wave][1] = r;  initP[wave][2] = c2;
      initP[wave][3] = c3; initP[wave][4] = c4; initP[wave][5] = c5;
    }
  }
  __syncthreads();
  const float n1 = (initP[0][0] + initP[1][0]) + (initP[2][0] + initP[3][0]);
  float t1 = (initP[0][1] + initP[1][1]) + (initP[2][1] + initP[3][1]);
  float t2 = (initP[0][2] + initP[1][2]) + (initP[2][2] + initP[3][2]);
  float t3 = (initP[0][3] + initP[1][3]) + (initP[2][3] + initP[3][3]);
  float t4 = (initP[0][4] + initP[1][4]) + (initP[2][4] + initP[3][4]);
  float t5 = (initP[0][5] + initP[1][5]) + (initP[2][5] + initP[3][5]);
  const float B1 = t1 + t1, C2 = t2 + t2, C3 = t3 + t3, C4 = t4 + t4, C5 = t5 + t5;

  const float e1 = scLDS[1].x;
  float4 sc2 = scLDS[2], sc3 = scLDS[3], sc4 = scLDS[4], sc5 = scLDS[5];
  const float D45x = d45LDS[5].x;  // 2*d4_5
  float4 scA = scLDS[6], scB = scLDS[7];
  float2 d45A = d45LDS[6], d45B = d45LDS[7];

  float n = n1, rm1, rm2, rm3, rm4, pp;
  float gr0 = 0.f, gr1 = 0.f;
  float4 rv = make_float4(0.f, 0.f, 0.f, 0.f);
  float4 hvr[4];  // store-data register ring (all indices compile-time constants)

#define BAR0 { asm volatile("s_waitcnt lgkmcnt(0)" ::: "memory"); __builtin_amdgcn_s_barrier(); }

  // ---- step 1
  {
    const float rinv = fast_rsq(fmaf(n, INVD, EPSV));
    n = fmaf(rinv, fmaf(rinv, n, B1), e1);
    hvr[1].x = rinv * s.x; hvr[1].y = rinv * s.y;
    hvr[1].z = rinv * s.z; hvr[1].w = rinv * s.w;
    h4[(size_t)SLOT4C * 1 + idx4] = hvr[1];
    s.x = hvr[1].x + w1v.x; s.y = hvr[1].y + w1v.y;
    s.z = hvr[1].z + w1v.z; s.w = hvr[1].w + w1v.w;
    pp = dpp_sum_reg(dot4(hvr[1], w[6]));  // G_6 partial
    rm1 = rinv;
    BAR0
  }
  // ---- step 2
  {
    if (lane == 63) Gp[2][wave] = pp;  // target 6
    const float rinv = fast_rsq(fmaf(n, INVD, EPSV));
    const float BB = fmaf(rm1, C2, sc2.y);
    n = fmaf(rinv, fmaf(rinv, n, BB), sc2.x);
    hvr[2].x = rinv * s.x; hvr[2].y = rinv * s.y;
    hvr[2].z = rinv * s.z; hvr[2].w = rinv * s.w;
    h4[(size_t)SLOT4C * 2 + idx4] = hvr[2];
    s.x = hvr[2].x + w[2].x; s.y = hvr[2].y + w[2].y;
    s.z = hvr[2].z + w[2].z; s.w = hvr[2].w + w[2].w;
    pp = dpp_sum_reg(dot4(hvr[2], w[7]));  // G_7 partial
    w[2] = h4[(size_t)SLOT4C * 19 + idx4];  // W_18
    rm2 = rm1; rm1 = rinv;
    BAR0
  }
  // ---- step 3
  {
    if (lane == 63) Gp[3][wave] = pp;  // target 7
    const float rinv = fast_rsq(fmaf(n, INVD, EPSV));
    const float BB = fmaf(rm1, fmaf(rm2, C3, sc3.z), sc3.y);
    n = fmaf(rinv, fmaf(rinv, n, BB), sc3.x);
    hvr[3].x = rinv * s.x; hvr[3].y = rinv * s.y;
    hvr[3].z = rinv * s.z; hvr[3].w = rinv * s.w;
    h4[(size_t)SLOT4C * 3 + idx4] = hvr[3];
    s.x = hvr[3].x + w[3].x; s.y = hvr[3].y + w[3].y;
    s.z = hvr[3].z + w[3].z; s.w = hvr[3].w + w[3].w;
    pp = dpp_sum_reg(dot4(hvr[3], w[8]));  // G_8 partial
    w[3] = h4[(size_t)SLOT4C * 20 + idx4];  // W_19
    rm3 = rm2; rm2 = rm1; rm1 = rinv;
    BAR0
  }
  // ---- step 4
  {
    if (lane == 63) Gp[0][wave] = pp;  // target 8
    const float rinv = fast_rsq(fmaf(n, INVD, EPSV));
    const float BB = fmaf(rm1, fmaf(rm2, fmaf(rm3, C4, sc4.w), sc4.z), sc4.y);
    n = fmaf(rinv, fmaf(rinv, n, BB), sc4.x);
    rv = *(const float4*)&Gp[2][0];  // target-6 partials
    hvr[0].x = rinv * s.x; hvr[0].y = rinv * s.y;
    hvr[0].z = rinv * s.z; hvr[0].w = rinv * s.w;
    h4[(size_t)SLOT4C * 4 + idx4] = hvr[0];
    s.x = hvr[0].x + w[4].x; s.y = hvr[0].y + w[4].y;
    s.z = hvr[0].z + w[4].z; s.w = hvr[0].w + w[4].w;
    pp = dpp_sum_reg(dot4(hvr[0], w[9]));  // G_9 partial
    w[4] = h4[(size_t)SLOT4C * 21 + idx4];  // W_20
    rm4 = rm3; rm3 = rm2; rm2 = rm1; rm1 = rinv;
    BAR0
  }
  // ---- step 5
  {
    if (lane == 63) Gp[1][wave] = pp;  // target 9
    const float rinv = fast_rsq(fmaf(n, INVD, EPSV));
    const float BB =
        fmaf(rm1, fmaf(rm2, fmaf(rm3, fmaf(rm4, C5, D45x), sc5.w), sc5.z), sc5.y);
    n = fmaf(rinv, fmaf(rinv, n, BB), sc5.x);
    { float gt = (rv.x + rv.y) + (rv.z + rv.w); gr0 = gt + gt; }  // 2*G_6
    rv = *(const float4*)&Gp[3][0];  // target-7 partials
    hvr[1].x = rinv * s.x; hvr[1].y = rinv * s.y;
    hvr[1].z = rinv * s.z; hvr[1].w = rinv * s.w;
    h4[(size_t)SLOT4C * 5 + idx4] = hvr[1];
    s.x = hvr[1].x + w[5].x; s.y = hvr[1].y + w[5].y;
    s.z = hvr[1].z + w[5].z; s.w = hvr[1].w + w[5].w;
    pp = dpp_sum_reg(dot4(hvr[1], w[10]));  // G_10 partial
    w[5] = h4[(size_t)SLOT4C * 22 + idx4];  // W_21
    rm4 = rm3; rm3 = rm2; rm2 = rm1; rm1 = rinv;
    BAR0
  }

// Steady step i>=6.  DS order: write pp | (combine prev rv) | read rv | body |
// read sc/d45 (2-step slack) | counted lgkmcnt(3)+barrier on odd steps.
#define STEP(I_, WS, W5S, GW, GR, SCR, D45R, GRU, GRW, HVI, BAR_)                    \
  {                                                                                  \
    const int i_ = (I_);                                                             \
    if (lane == 63) Gp[GW][wave] = pp;                                               \
    { float gt_ = (rv.x + rv.y) + (rv.z + rv.w); GRW = gt_ + gt_; }                  \
    rv = *(const float4*)&Gp[GR][0];                                                 \
    const float rinv = fast_rsq(fmaf(n, INVD, EPSV));                                \
    const float BB = fmaf(                                                           \
        rm1, fmaf(rm2, fmaf(rm3, fmaf(rm4, (D45R).y + (GRU), (D45R).x), (SCR).w),    \
                  (SCR).z), (SCR).y);                                                \
    n = fmaf(rinv, fmaf(rinv, n, BB), (SCR).x);                                      \
    hvr[HVI].x = rinv * s.x; hvr[HVI].y = rinv * s.y;                                \
    hvr[HVI].z = rinv * s.z; hvr[HVI].w = rinv * s.w;                                \
    h4[(size_t)SLOT4C * i_ + idx4] = hvr[HVI];                                       \
    s.x = hvr[HVI].x + w[WS].x; s.y = hvr[HVI].y + w[WS].y;                          \
    s.z = hvr[HVI].z + w[WS].z; s.w = hvr[HVI].w + w[WS].w;                          \
    pp = dpp_sum_reg(dot4(hvr[HVI], w[W5S]));                                        \
    const int ipf_ = (i_ + 16 < T_STEPS) ? (i_ + 16) : (T_STEPS - 1);                \
    w[WS] = h4[(size_t)SLOT4C * (ipf_ + 1) + idx4];                                  \
    const int isc_ = (i_ + 2 < T_STEPS) ? (i_ + 2) : (T_STEPS - 1);                  \
    SCR = scLDS[isc_];                                                               \
    D45R = d45LDS[isc_];                                                             \
    rm4 = rm3; rm3 = rm2; rm2 = rm1; rm1 = rinv;                                     \
    if (BAR_) { asm volatile("s_waitcnt lgkmcnt(3)" ::: "memory");                   \
                __builtin_amdgcn_s_barrier(); }                                      \
  }

  // main loop: i = 6..2037 in chunks of 16 (ii ≡ 6 mod 16); HVI = i&3
  for (int ii = 6; ii < 2038; ii += 16) {
    STEP(ii + 0,  6, 11, 2, 0, scA, d45A, gr0, gr1, 2, 0)
    STEP(ii + 1,  7, 12, 3, 1, scB, d45B, gr1, gr0, 3, 1)
    STEP(ii + 2,  8, 13, 0, 2, scA, d45A, gr0, gr1, 0, 0)
    STEP(ii + 3,  9, 14, 1, 3, scB, d45B, gr1, gr0, 1, 1)
    STEP(ii + 4, 10, 15, 2, 0, scA, d45A, gr0, gr1, 2, 0)
    STEP(ii + 5, 11,  0, 3, 1, scB, d45B, gr1, gr0, 3, 1)
    STEP(ii + 6, 12,  1, 0, 2, scA, d45A, gr0, gr1, 0, 0)
    STEP(ii + 7, 13,  2, 1, 3, scB, d45B, gr1, gr0, 1, 1)
    STEP(ii + 8, 14,  3, 2, 0, scA, d45A, gr0, gr1, 2, 0)
    STEP(ii + 9, 15,  4, 3, 1, scB, d45B, gr1, gr0, 3, 1)
    STEP(ii + 10, 0,  5, 0, 2, scA, d45A, gr0, gr1, 0, 0)
    STEP(ii + 11, 1,  6, 1, 3, scB, d45B, gr1, gr0, 1, 1)
    STEP(ii + 12, 2,  7, 2, 0, scA, d45A, gr0, gr1, 2, 0)
    STEP(ii + 13, 3,  8, 3, 1, scB, d45B, gr1, gr0, 3, 1)
    STEP(ii + 14, 4,  9, 0, 2, scA, d45A, gr0, gr1, 0, 0)
    STEP(ii + 15, 5, 10, 1, 3, scB, d45B, gr1, gr0, 1, 1)
  }
  // tail: i = 2038..2047 (continues pattern, 2038 ≡ 6 mod 16)
  STEP(2038,  6, 11, 2, 0, scA, d45A, gr0, gr1, 2, 0)
  STEP(2039,  7, 12, 3, 1, scB, d45B, gr1, gr0, 3, 1)
  STEP(2040,  8, 13, 0, 2, scA, d45A, gr0, gr1, 0, 0)
  STEP(2041,  9, 14, 1, 3, scB, d45B, gr1, gr0, 1, 1)
  STEP(2042, 10, 15, 2, 0, scA, d45A, gr0, gr1, 2, 0)
  STEP(2043, 11,  0, 3, 1, scB, d45B, gr1, gr0, 3, 1)
  STEP(2044, 12,  1, 0, 2, scA, d45A, gr0, gr1, 0, 0)
  STEP(2045, 13,  2, 1, 3, scB, d45B, gr1, gr0, 1, 1)
  STEP(2046, 14,  3, 2, 0, scA, d45A, gr0, gr1, 2, 0)
  STEP(2047, 15,  4, 3, 1, scB, d45B, gr1, gr0, 3, 1)
#undef STEP
#undef BAR0

  // final: h_2048 = rinv * s -> slot 2048
  const float rinvT = fast_rsq(fmaf(n, INVD, EPSV));
  float4 o;
  o.x = rinvT * s.x; o.y = rinvT * s.y; o.z = rinvT * s.z; o.w = rinvT * s.w;
  h4[(size_t)SLOT4C * T_STEPS + idx4] = o;
}

// ---------------- outs[t] = h_{t+1} * silu(h_{t+1}) ----------------
__global__ __launch_bounds__(256) void silu_kernel(const float4* __restrict__ hsrc,
                                                   float4* __restrict__ out4, int n4) {
  int i = blockIdx.x * blockDim.x + threadIdx.x;
  if (i >= n4) return;
  float4 h = hsrc[i];
  float4 o;
  o.x = h.x * h.x / (1.f + __expf(-h.x));
  o.y = h.y * h.y / (1.f + __expf(-h.y));
  o.z = h.z * h.z / (1.f + __expf(-h.z));
  o.w = h.w * h.w / (1.f + __expf(-h.w));
  out4[i] = o;
}

extern "C" void kernel_launch(void* const* d_in, const int* in_sizes, int n_in,
                              void* d_out, int out_size, void* d_ws, size_t ws_size,
                              hipStream_t stream) {
  (void)in_sizes; (void)n_in; (void)d_ws; (void)ws_size; (void)out_size;
  const float* x = (const float*)d_in[0];
  const float* h0 = (const float*)d_in[1];
  const float* W = (const float*)d_in[2];
  const float* bias = (const float*)d_in[3];
  const float* log_alpha = (const float*)d_in[4];

  float* out = (float*)d_out;                               // outs region [T][B][D]
  float* hreg = out + (size_t)T_STEPS * BATCH * DIM;        // h region [T+1][B][D]
  // staging overlays the outs region (consumed before scan/silu touch it)
  __hip_bfloat16* xb = (__hip_bfloat16*)d_out;
  __hip_bfloat16* wb = (__hip_bfloat16*)((char*)d_out + (size_t)T_STEPS * BATCH * DIM * 2);
  float4* scal4 = (float4*)(out + (size_t)26 * 1024 * 1024);  // 104 MB offset
  float2* d45g = (float2*)(out + (size_t)27 * 1024 * 1024);   // 108 MB offset

  const int nx8 = T_STEPS * BATCH * DIM / 8;
  const int nw8 = DIM * DIM / 8;
  cvt_kernel<<<nx8 / 256, 256, 0, stream>>>(x, (bf16x8pack*)xb, nx8);
  cvt_kernel<<<nw8 / 256, 256, 0, stream>>>(W, (bf16x8pack*)wb, nw8);

  dim3 ggrid(DIM / 128, (T_STEPS * BATCH) / 128);
  gemm_kernel<<<ggrid, 256, 0, stream>>>(xb, wb, bias, log_alpha, hreg);

  dots_kernel<<<T_STEPS * BATCH, 64, 0, stream>>>(hreg, scal4, d45g);

  scan_kernel<<<BATCH, 256, 0, stream>>>(h0, scal4, d45g, hreg);

  const int n4 = T_STEPS * BATCH * DIM / 4;
  silu_kernel<<<n4 / 256, 256, 0, stream>>>((const float4*)(hreg + BATCH * DIM),
                                            (float4*)out, n4);
}